// Round 4
// baseline (282.316 us; speedup 1.0000x reference)
//
#include <hip/hip_runtime.h>

// B=8, T=1024, D=128, TEMP=0.1, WEIGHT=1.0. 56 ordered pairs (i,j), i!=j.
// z1[t,s] = DOTSCALE*(e1_t . e2_s) - ns[s], ns = |e2_s|^2*(1/12.8)*log2e (row-const dropped)
// p = exp2(z1); nn_t = sum p*e2_s / sum p
// z2[t,s] = DOTSCALE*(nn_t . e1_s) - ns_i[s]; pred = sum exp2(z2)*sp_s / sum exp2(z2)
// loss = mean (pred - sp_t)^2.  No max-subtraction: z provably in [-40,+15].
//
// R4: s-range split across 2 waves/block (8 s-tiles each) -> 3.5 waves/SIMD
// (was 1.75, latency-bound). Partial L / O combined via LDS outside hot loop.
// finalize fused via last-block atomic counter; acc init fused into convert.

#define T_ 1024
#define D_ 128
#define NPAIR 56
#define DOTSCALE 0.22542110013890052f // (2/12.8)*log2(e)
#define NSCALE 0.11271055006945026f   // (1/12.8)*log2(e)

typedef short short8 __attribute__((ext_vector_type(8)));
typedef unsigned short u16x8 __attribute__((ext_vector_type(8)));
typedef float f32x16 __attribute__((ext_vector_type(16)));

#define BATCH_STRIDE 131072  // shorts per batch in frag layouts (256 chunks * 512)

__device__ __forceinline__ unsigned short f2bf(float f) {
  unsigned u = __float_as_uint(f);
  u += 0x7fff + ((u >> 16) & 1);  // RNE
  return (unsigned short)(u >> 16);
}
__device__ __forceinline__ float bf2f(unsigned short v) {
  return __uint_as_float(((unsigned)v) << 16);
}

__device__ __forceinline__ float waveSum(float v) {
#pragma unroll
  for (int k = 32; k >= 1; k >>= 1) v += __shfl_xor(v, k, 64);
  return v;
}
__device__ __forceinline__ float halfSum(float v) {  // sum within each 32-lane half
  v += __shfl_xor(v, 1, 64); v += __shfl_xor(v, 2, 64);
  v += __shfl_xor(v, 4, 64); v += __shfl_xor(v, 8, 64);
  v += __shfl_xor(v, 16, 64);
  return v;
}

// ---- fused: fp32 -> bf16 frag layouts + norms + steps + ws init ----
// fragA (row-frag): chunk c = (t>>5)*8 + (d>>4); lane = ((d>>3)&1)*32 + (t&31); elem = d&7
// fragT (V^T frag): chunk c = (d>>5)*64 + (t>>4); lane = ((t>>3)&1)*32 + (d&31); elem = t&7
__global__ __launch_bounds__(256) void convert_kernel(
    const float* __restrict__ embs, const int* __restrict__ fi,
    const int* __restrict__ vl, unsigned short* __restrict__ ebfF,
    unsigned short* __restrict__ ebfT, float* __restrict__ ns,
    float* __restrict__ steps, float* __restrict__ acc,
    unsigned* __restrict__ cnt) {
  __shared__ unsigned short tileS[32 * 136];
  __shared__ float psum[32][8];
  const int b = blockIdx.x >> 5;
  const int t0 = (blockIdx.x & 31) * 32;
  const int tid = threadIdx.x;
  const int row = tid >> 3, seg = tid & 7;

  if (blockIdx.x == 0 && tid == 0) { acc[0] = 0.f; cnt[0] = 0u; }

  const float* src = embs + (size_t)(b * T_ + t0 + row) * D_ + seg * 16;
  float4 g[4];
#pragma unroll
  for (int k = 0; k < 4; k++) g[k] = ((const float4*)src)[k];
  float s = 0.f;
  unsigned short v[16];
#pragma unroll
  for (int k = 0; k < 4; k++) {
    s += g[k].x * g[k].x + g[k].y * g[k].y + g[k].z * g[k].z + g[k].w * g[k].w;
    v[k * 4 + 0] = f2bf(g[k].x); v[k * 4 + 1] = f2bf(g[k].y);
    v[k * 4 + 2] = f2bf(g[k].z); v[k * 4 + 3] = f2bf(g[k].w);
  }
  psum[row][seg] = s;

  unsigned short* dstA = ebfF + (size_t)b * BATCH_STRIDE + (size_t)((t0 >> 5) * 8 + seg) * 512;
  *(u16x8*)(dstA + row * 8) = *(const u16x8*)&v[0];
  *(u16x8*)(dstA + (32 + row) * 8) = *(const u16x8*)&v[8];

  *(u16x8*)&tileS[row * 136 + seg * 16] = *(const u16x8*)&v[0];
  *(u16x8*)&tileS[row * 136 + seg * 16 + 8] = *(const u16x8*)&v[8];
  __syncthreads();

  if (tid < 32) {
    float t = 0.f;
#pragma unroll
    for (int k = 0; k < 8; k++) t += psum[tid][k];
    int gr = b * T_ + t0 + tid;
    ns[gr] = t * NSCALE;
    steps[gr] = (float)fi[gr] / (float)vl[b];
  }

  const int c8 = tid >> 5;
  const int d0t = (c8 & 3) * 32, sc = c8 >> 2;
  const int chunk = (d0t >> 5) * 64 + (t0 >> 4) + sc;
  unsigned short* dstT = ebfT + (size_t)b * BATCH_STRIDE + (size_t)chunk * 512;
  const int dd = d0t + (tid & 31);
#pragma unroll
  for (int half = 0; half < 2; half++) {
    const int lane = half * 32 + (tid & 31);
    const int sl = sc * 16 + half * 8;
    u16x8 w;
#pragma unroll
    for (int jj = 0; jj < 8; jj++) w[jj] = tileS[(sl + jj) * 136 + dd];
    *(u16x8*)(dstT + lane * 8) = w;
  }
}

__global__ __launch_bounds__(128, 4) void tcc_main(
    const unsigned short* __restrict__ ebfF, const unsigned short* __restrict__ ebfT,
    const float* __restrict__ ns, const float* __restrict__ steps,
    float* __restrict__ loss_acc, unsigned* __restrict__ cnt,
    float* __restrict__ out) {
  __shared__ unsigned short pbuf[2][2304];   // per-wave p transpose, stride 72
  __shared__ unsigned short nnb[32 * 136];   // o-reduce (bf16) then nn A-frags
  __shared__ float Lp1[2][32];
  __shared__ float Lp2[2][32], Tp2[2][32];

  const int bx = blockIdx.x;
  const int pair = bx >> 5;
  const int tile = bx & 31;
  const int i = pair / 7;
  const int r = pair % 7;
  const int j = r + (r >= i ? 1 : 0);
  const int t0 = tile * 32;
  const int tid = threadIdx.x;
  const int w = tid >> 6;            // wave 0/1: s-tiles 8w .. 8w+7
  const int l = tid & 63;
  const int l31 = l & 31;
  const int lh = l >> 5;

  // Q A-frags: e1 rows t0..t0+31 (both waves load the same rows)
  short8 qf[8];
  {
    const unsigned short* qb = ebfF + (size_t)i * BATCH_STRIDE + (size_t)((t0 >> 5) * 8) * 512 + l * 8;
#pragma unroll
    for (int kc = 0; kc < 8; kc++) qf[kc] = *(const short8*)(qb + kc * 512);
  }

  f32x16 o[4];
#pragma unroll
  for (int n2 = 0; n2 < 4; n2++)
#pragma unroll
    for (int z = 0; z < 16; z++) o[n2][z] = 0.f;
  float L1a[16];
#pragma unroll
  for (int z = 0; z < 16; z++) L1a[z] = 0.f;

  const unsigned short* kb1 = ebfF + (size_t)j * BATCH_STRIDE + l * 8;
  const unsigned short* vb1 = ebfT + (size_t)j * BATCH_STRIDE + l * 8;
  const float* nsj = ns + j * T_;
  unsigned short* pb = pbuf[w];

  // ---------------- phase 1: Q=e1, K=V=e2; 8 s-tiles per wave, no barriers ----------------
  for (int st = w * 8; st < w * 8 + 8; st++) {
    f32x16 c0, c1;
#pragma unroll
    for (int z = 0; z < 16; z++) { c0[z] = 0.f; c1[z] = 0.f; }
    const unsigned short* kp = kb1 + (size_t)(st * 16) * 512;
#pragma unroll
    for (int kc = 0; kc < 8; kc++) {
      short8 b0 = *(const short8*)(kp + kc * 512);
      short8 b1 = *(const short8*)(kp + (8 + kc) * 512);
      c0 = __builtin_amdgcn_mfma_f32_32x32x16_bf16(qf[kc], b0, c0, 0, 0, 0);
      c1 = __builtin_amdgcn_mfma_f32_32x32x16_bf16(qf[kc], b1, c1, 0, 0, 0);
    }
    const float ns0 = nsj[st * 64 + l31];
    const float ns1 = nsj[st * 64 + 32 + l31];
#pragma unroll
    for (int rg = 0; rg < 16; rg++) {
      const int row = (rg & 3) + 8 * (rg >> 2) + 4 * lh;
      float p0 = __builtin_amdgcn_exp2f(c0[rg] * DOTSCALE - ns0);
      float p1 = __builtin_amdgcn_exp2f(c1[rg] * DOTSCALE - ns1);
      L1a[rg] += p0 + p1;
      pb[row * 72 + l31] = f2bf(p0);
      pb[row * 72 + 32 + l31] = f2bf(p1);
    }
    short8 pf[4];
#pragma unroll
    for (int kc2 = 0; kc2 < 4; kc2++)
      pf[kc2] = *(const short8*)(pb + l31 * 72 + kc2 * 16 + lh * 8);
    const unsigned short* vp = vb1 + (size_t)(st * 4) * 512;
#pragma unroll
    for (int n2 = 0; n2 < 4; n2++) {
#pragma unroll
      for (int kc2 = 0; kc2 < 4; kc2++) {
        short8 bv = *(const short8*)(vp + (size_t)(n2 * 64 + kc2) * 512);
        o[n2] = __builtin_amdgcn_mfma_f32_32x32x16_bf16(pf[kc2], bv, o[n2], 0, 0, 0);
      }
    }
  }

  // ---- cross-wave combine of L and O; compute nn A-frags ----
#pragma unroll
  for (int rg = 0; rg < 16; rg++) {
    const int row = (rg & 3) + 8 * (rg >> 2) + 4 * lh;
    float Ls = halfSum(L1a[rg]);
    if (l31 == 0) Lp1[w][row] = Ls;
  }
  if (w == 1) {
#pragma unroll
    for (int n2 = 0; n2 < 4; n2++)
#pragma unroll
      for (int rg = 0; rg < 16; rg++) {
        const int row = (rg & 3) + 8 * (rg >> 2) + 4 * lh;
        nnb[row * 136 + n2 * 32 + l31] = f2bf(o[n2][rg]);
      }
  }
  __syncthreads();
  if (w == 0) {
#pragma unroll
    for (int rg = 0; rg < 16; rg++) {
      const int row = (rg & 3) + 8 * (rg >> 2) + 4 * lh;
      float inv = 1.0f / (Lp1[0][row] + Lp1[1][row]);
#pragma unroll
      for (int n2 = 0; n2 < 4; n2++) {
        float ot = o[n2][rg] + bf2f(nnb[row * 136 + n2 * 32 + l31]);
        nnb[row * 136 + n2 * 32 + l31] = f2bf(ot * inv);
      }
    }
  }
  __syncthreads();
  short8 qf2[8];
#pragma unroll
  for (int kc = 0; kc < 8; kc++)
    qf2[kc] = *(const short8*)(nnb + l31 * 136 + kc * 16 + lh * 8);

  // ---------------- phase 2: Q=nn, K=e1, V=sp scalar; 8 s-tiles per wave ----------------
  float L2a[16], tpa[16];
#pragma unroll
  for (int z = 0; z < 16; z++) { L2a[z] = 0.f; tpa[z] = 0.f; }
  const unsigned short* kb2 = ebfF + (size_t)i * BATCH_STRIDE + l * 8;
  const float* nsi = ns + i * T_;
  const float* spi = steps + i * T_;

  for (int st = w * 8; st < w * 8 + 8; st++) {
    f32x16 c0, c1;
#pragma unroll
    for (int z = 0; z < 16; z++) { c0[z] = 0.f; c1[z] = 0.f; }
    const unsigned short* kp = kb2 + (size_t)(st * 16) * 512;
#pragma unroll
    for (int kc = 0; kc < 8; kc++) {
      short8 b0 = *(const short8*)(kp + kc * 512);
      short8 b1 = *(const short8*)(kp + (8 + kc) * 512);
      c0 = __builtin_amdgcn_mfma_f32_32x32x16_bf16(qf2[kc], b0, c0, 0, 0, 0);
      c1 = __builtin_amdgcn_mfma_f32_32x32x16_bf16(qf2[kc], b1, c1, 0, 0, 0);
    }
    const float ns0 = nsi[st * 64 + l31], sp0 = spi[st * 64 + l31];
    const float ns1 = nsi[st * 64 + 32 + l31], sp1 = spi[st * 64 + 32 + l31];
#pragma unroll
    for (int rg = 0; rg < 16; rg++) {
      float p0 = __builtin_amdgcn_exp2f(c0[rg] * DOTSCALE - ns0);
      float p1 = __builtin_amdgcn_exp2f(c1[rg] * DOTSCALE - ns1);
      L2a[rg] += p0 + p1;
      tpa[rg] += p0 * sp0 + p1 * sp1;
    }
  }

  // ---- cross-wave combine + MSE + fused finalize ----
#pragma unroll
  for (int rg = 0; rg < 16; rg++) {
    const int row = (rg & 3) + 8 * (rg >> 2) + 4 * lh;
    float Ls = halfSum(L2a[rg]);
    float Ts = halfSum(tpa[rg]);
    if (l31 == 0) { Lp2[w][row] = Ls; Tp2[w][row] = Ts; }
  }
  __syncthreads();
  if (w == 0) {
    float local = 0.f;
    if (l < 32) {
      float Lv = Lp2[0][l] + Lp2[1][l];
      float Tv = Tp2[0][l] + Tp2[1][l];
      float pred = Tv / Lv;
      float tt = steps[i * T_ + t0 + l];
      float d = pred - tt;
      local = d * d;
    }
    local = waveSum(local);
    if (l == 0) {
      atomicAdd(loss_acc, local);
      __threadfence();
      unsigned old = atomicAdd(cnt, 1u);
      if (old == (unsigned)(gridDim.x - 1)) {
        float v = atomicAdd(loss_acc, 0.0f);   // device-scope atomic read
        out[0] = v * (1.0f / (float)(NPAIR * T_));
      }
    }
  }
}

extern "C" void kernel_launch(void* const* d_in, const int* in_sizes, int n_in,
                              void* d_out, int out_size, void* d_ws, size_t ws_size,
                              hipStream_t stream) {
  const float* embs = (const float*)d_in[0];
  const int* frame_idxs = (const int*)d_in[1];
  const int* video_len = (const int*)d_in[2];
  float* out = (float*)d_out;

  char* ws = (char*)d_ws;
  float* acc = (float*)ws;                                     // @0
  unsigned* cnt = (unsigned*)(ws + 512);                       // @512
  float* ns = (float*)(ws + 1024);                             // 8192 f32
  float* steps = (float*)(ws + 1024 + 32768);                  // 8192 f32
  unsigned short* ebfF = (unsigned short*)(ws + 1024 + 65536); // 2 MB frag layout
  unsigned short* ebfT = ebfF + (size_t)8 * BATCH_STRIDE;      // 2 MB transposed frag

  convert_kernel<<<dim3(256), dim3(256), 0, stream>>>(embs, frame_idxs, video_len,
                                                      ebfF, ebfT, ns, steps, acc, cnt);
  tcc_main<<<dim3(NPAIR * 32), dim3(128), 0, stream>>>(ebfF, ebfT, ns, steps, acc, cnt, out);
}

// Round 5
// 181.235 us; speedup vs baseline: 1.5577x; 1.5577x over previous
//
#include <hip/hip_runtime.h>

// B=8, T=1024, D=128, TEMP=0.1, WEIGHT=1.0. 56 ordered pairs (i,j), i!=j.
// z1[t,s] = DOTSCALE*(e1_t . e2_s) - ns[s], ns = |e2_s|^2*(1/12.8)*log2e (row-const dropped)
// p = exp2(z1); nn_t = sum p*e2_s / sum p
// z2[t,s] = DOTSCALE*(nn_t . e1_s) - ns_i[s]; pred = sum exp2(z2)*sp_s / sum exp2(z2)
// loss = mean (pred - sp_t)^2.  No max-subtraction: z provably in [-40,+15].
//
// R5 = R4 structure with the VGPR cap fixed: __launch_bounds__(128,2).
// R4's (128,4) forced 64 arch VGPRs -> scratch spills (WRITE_SIZE 126MB) -> 2x regress.
// Kernel genuinely needs ~160-190 VGPRs; at ~160 HW gives 3 waves/SIMD naturally.

#define T_ 1024
#define D_ 128
#define NPAIR 56
#define DOTSCALE 0.22542110013890052f // (2/12.8)*log2(e)
#define NSCALE 0.11271055006945026f   // (1/12.8)*log2(e)

typedef short short8 __attribute__((ext_vector_type(8)));
typedef unsigned short u16x8 __attribute__((ext_vector_type(8)));
typedef float f32x16 __attribute__((ext_vector_type(16)));

#define BATCH_STRIDE 131072  // shorts per batch in frag layouts (256 chunks * 512)

__device__ __forceinline__ unsigned short f2bf(float f) {
  unsigned u = __float_as_uint(f);
  u += 0x7fff + ((u >> 16) & 1);  // RNE
  return (unsigned short)(u >> 16);
}
__device__ __forceinline__ float bf2f(unsigned short v) {
  return __uint_as_float(((unsigned)v) << 16);
}

__device__ __forceinline__ float waveSum(float v) {
#pragma unroll
  for (int k = 32; k >= 1; k >>= 1) v += __shfl_xor(v, k, 64);
  return v;
}
__device__ __forceinline__ float halfSum(float v) {  // sum within each 32-lane half
  v += __shfl_xor(v, 1, 64); v += __shfl_xor(v, 2, 64);
  v += __shfl_xor(v, 4, 64); v += __shfl_xor(v, 8, 64);
  v += __shfl_xor(v, 16, 64);
  return v;
}

// ---- fused: fp32 -> bf16 frag layouts + norms + steps + ws init ----
// fragA (row-frag): chunk c = (t>>5)*8 + (d>>4); lane = ((d>>3)&1)*32 + (t&31); elem = d&7
// fragT (V^T frag): chunk c = (d>>5)*64 + (t>>4); lane = ((t>>3)&1)*32 + (d&31); elem = t&7
__global__ __launch_bounds__(256) void convert_kernel(
    const float* __restrict__ embs, const int* __restrict__ fi,
    const int* __restrict__ vl, unsigned short* __restrict__ ebfF,
    unsigned short* __restrict__ ebfT, float* __restrict__ ns,
    float* __restrict__ steps, float* __restrict__ acc,
    unsigned* __restrict__ cnt) {
  __shared__ unsigned short tileS[32 * 136];
  __shared__ float psum[32][8];
  const int b = blockIdx.x >> 5;
  const int t0 = (blockIdx.x & 31) * 32;
  const int tid = threadIdx.x;
  const int row = tid >> 3, seg = tid & 7;

  if (blockIdx.x == 0 && tid == 0) { acc[0] = 0.f; cnt[0] = 0u; }

  const float* src = embs + (size_t)(b * T_ + t0 + row) * D_ + seg * 16;
  float4 g[4];
#pragma unroll
  for (int k = 0; k < 4; k++) g[k] = ((const float4*)src)[k];
  float s = 0.f;
  unsigned short v[16];
#pragma unroll
  for (int k = 0; k < 4; k++) {
    s += g[k].x * g[k].x + g[k].y * g[k].y + g[k].z * g[k].z + g[k].w * g[k].w;
    v[k * 4 + 0] = f2bf(g[k].x); v[k * 4 + 1] = f2bf(g[k].y);
    v[k * 4 + 2] = f2bf(g[k].z); v[k * 4 + 3] = f2bf(g[k].w);
  }
  psum[row][seg] = s;

  unsigned short* dstA = ebfF + (size_t)b * BATCH_STRIDE + (size_t)((t0 >> 5) * 8 + seg) * 512;
  *(u16x8*)(dstA + row * 8) = *(const u16x8*)&v[0];
  *(u16x8*)(dstA + (32 + row) * 8) = *(const u16x8*)&v[8];

  *(u16x8*)&tileS[row * 136 + seg * 16] = *(const u16x8*)&v[0];
  *(u16x8*)&tileS[row * 136 + seg * 16 + 8] = *(const u16x8*)&v[8];
  __syncthreads();

  if (tid < 32) {
    float t = 0.f;
#pragma unroll
    for (int k = 0; k < 8; k++) t += psum[tid][k];
    int gr = b * T_ + t0 + tid;
    ns[gr] = t * NSCALE;
    steps[gr] = (float)fi[gr] / (float)vl[b];
  }

  const int c8 = tid >> 5;
  const int d0t = (c8 & 3) * 32, sc = c8 >> 2;
  const int chunk = (d0t >> 5) * 64 + (t0 >> 4) + sc;
  unsigned short* dstT = ebfT + (size_t)b * BATCH_STRIDE + (size_t)chunk * 512;
  const int dd = d0t + (tid & 31);
#pragma unroll
  for (int half = 0; half < 2; half++) {
    const int lane = half * 32 + (tid & 31);
    const int sl = sc * 16 + half * 8;
    u16x8 w;
#pragma unroll
    for (int jj = 0; jj < 8; jj++) w[jj] = tileS[(sl + jj) * 136 + dd];
    *(u16x8*)(dstT + lane * 8) = w;
  }
}

__global__ __launch_bounds__(128, 2) void tcc_main(
    const unsigned short* __restrict__ ebfF, const unsigned short* __restrict__ ebfT,
    const float* __restrict__ ns, const float* __restrict__ steps,
    float* __restrict__ loss_acc, unsigned* __restrict__ cnt,
    float* __restrict__ out) {
  __shared__ unsigned short pbuf[2][2304];   // per-wave p transpose, stride 72
  __shared__ unsigned short nnb[32 * 136];   // o-reduce (bf16) then nn A-frags
  __shared__ float Lp1[2][32];
  __shared__ float Lp2[2][32], Tp2[2][32];

  const int bx = blockIdx.x;
  const int pair = bx >> 5;
  const int tile = bx & 31;
  const int i = pair / 7;
  const int r = pair % 7;
  const int j = r + (r >= i ? 1 : 0);
  const int t0 = tile * 32;
  const int tid = threadIdx.x;
  const int w = tid >> 6;            // wave 0/1: s-tiles 8w .. 8w+7
  const int l = tid & 63;
  const int l31 = l & 31;
  const int lh = l >> 5;

  // Q A-frags: e1 rows t0..t0+31 (both waves load the same rows)
  short8 qf[8];
  {
    const unsigned short* qb = ebfF + (size_t)i * BATCH_STRIDE + (size_t)((t0 >> 5) * 8) * 512 + l * 8;
#pragma unroll
    for (int kc = 0; kc < 8; kc++) qf[kc] = *(const short8*)(qb + kc * 512);
  }

  f32x16 o[4];
#pragma unroll
  for (int n2 = 0; n2 < 4; n2++)
#pragma unroll
    for (int z = 0; z < 16; z++) o[n2][z] = 0.f;
  float L1a[16];
#pragma unroll
  for (int z = 0; z < 16; z++) L1a[z] = 0.f;

  const unsigned short* kb1 = ebfF + (size_t)j * BATCH_STRIDE + l * 8;
  const unsigned short* vb1 = ebfT + (size_t)j * BATCH_STRIDE + l * 8;
  const float* nsj = ns + j * T_;
  unsigned short* pb = pbuf[w];

  // ---------------- phase 1: Q=e1, K=V=e2; 8 s-tiles per wave, no barriers ----------------
  for (int st = w * 8; st < w * 8 + 8; st++) {
    f32x16 c0, c1;
#pragma unroll
    for (int z = 0; z < 16; z++) { c0[z] = 0.f; c1[z] = 0.f; }
    const unsigned short* kp = kb1 + (size_t)(st * 16) * 512;
#pragma unroll
    for (int kc = 0; kc < 8; kc++) {
      short8 b0 = *(const short8*)(kp + kc * 512);
      short8 b1 = *(const short8*)(kp + (8 + kc) * 512);
      c0 = __builtin_amdgcn_mfma_f32_32x32x16_bf16(qf[kc], b0, c0, 0, 0, 0);
      c1 = __builtin_amdgcn_mfma_f32_32x32x16_bf16(qf[kc], b1, c1, 0, 0, 0);
    }
    const float ns0 = nsj[st * 64 + l31];
    const float ns1 = nsj[st * 64 + 32 + l31];
#pragma unroll
    for (int rg = 0; rg < 16; rg++) {
      const int row = (rg & 3) + 8 * (rg >> 2) + 4 * lh;
      float p0 = __builtin_amdgcn_exp2f(c0[rg] * DOTSCALE - ns0);
      float p1 = __builtin_amdgcn_exp2f(c1[rg] * DOTSCALE - ns1);
      L1a[rg] += p0 + p1;
      pb[row * 72 + l31] = f2bf(p0);
      pb[row * 72 + 32 + l31] = f2bf(p1);
    }
    short8 pf[4];
#pragma unroll
    for (int kc2 = 0; kc2 < 4; kc2++)
      pf[kc2] = *(const short8*)(pb + l31 * 72 + kc2 * 16 + lh * 8);
    const unsigned short* vp = vb1 + (size_t)(st * 4) * 512;
#pragma unroll
    for (int n2 = 0; n2 < 4; n2++) {
#pragma unroll
      for (int kc2 = 0; kc2 < 4; kc2++) {
        short8 bv = *(const short8*)(vp + (size_t)(n2 * 64 + kc2) * 512);
        o[n2] = __builtin_amdgcn_mfma_f32_32x32x16_bf16(pf[kc2], bv, o[n2], 0, 0, 0);
      }
    }
  }

  // ---- cross-wave combine of L and O; compute nn A-frags ----
#pragma unroll
  for (int rg = 0; rg < 16; rg++) {
    const int row = (rg & 3) + 8 * (rg >> 2) + 4 * lh;
    float Ls = halfSum(L1a[rg]);
    if (l31 == 0) Lp1[w][row] = Ls;
  }
  if (w == 1) {
#pragma unroll
    for (int n2 = 0; n2 < 4; n2++)
#pragma unroll
      for (int rg = 0; rg < 16; rg++) {
        const int row = (rg & 3) + 8 * (rg >> 2) + 4 * lh;
        nnb[row * 136 + n2 * 32 + l31] = f2bf(o[n2][rg]);
      }
  }
  __syncthreads();
  if (w == 0) {
#pragma unroll
    for (int rg = 0; rg < 16; rg++) {
      const int row = (rg & 3) + 8 * (rg >> 2) + 4 * lh;
      float inv = 1.0f / (Lp1[0][row] + Lp1[1][row]);
#pragma unroll
      for (int n2 = 0; n2 < 4; n2++) {
        float ot = o[n2][rg] + bf2f(nnb[row * 136 + n2 * 32 + l31]);
        nnb[row * 136 + n2 * 32 + l31] = f2bf(ot * inv);
      }
    }
  }
  __syncthreads();
  short8 qf2[8];
#pragma unroll
  for (int kc = 0; kc < 8; kc++)
    qf2[kc] = *(const short8*)(nnb + l31 * 136 + kc * 16 + lh * 8);

  // ---------------- phase 2: Q=nn, K=e1, V=sp scalar; 8 s-tiles per wave ----------------
  float L2a[16], tpa[16];
#pragma unroll
  for (int z = 0; z < 16; z++) { L2a[z] = 0.f; tpa[z] = 0.f; }
  const unsigned short* kb2 = ebfF + (size_t)i * BATCH_STRIDE + l * 8;
  const float* nsi = ns + i * T_;
  const float* spi = steps + i * T_;

  for (int st = w * 8; st < w * 8 + 8; st++) {
    f32x16 c0, c1;
#pragma unroll
    for (int z = 0; z < 16; z++) { c0[z] = 0.f; c1[z] = 0.f; }
    const unsigned short* kp = kb2 + (size_t)(st * 16) * 512;
#pragma unroll
    for (int kc = 0; kc < 8; kc++) {
      short8 b0 = *(const short8*)(kp + kc * 512);
      short8 b1 = *(const short8*)(kp + (8 + kc) * 512);
      c0 = __builtin_amdgcn_mfma_f32_32x32x16_bf16(qf2[kc], b0, c0, 0, 0, 0);
      c1 = __builtin_amdgcn_mfma_f32_32x32x16_bf16(qf2[kc], b1, c1, 0, 0, 0);
    }
    const float ns0 = nsi[st * 64 + l31], sp0 = spi[st * 64 + l31];
    const float ns1 = nsi[st * 64 + 32 + l31], sp1 = spi[st * 64 + 32 + l31];
#pragma unroll
    for (int rg = 0; rg < 16; rg++) {
      float p0 = __builtin_amdgcn_exp2f(c0[rg] * DOTSCALE - ns0);
      float p1 = __builtin_amdgcn_exp2f(c1[rg] * DOTSCALE - ns1);
      L2a[rg] += p0 + p1;
      tpa[rg] += p0 * sp0 + p1 * sp1;
    }
  }

  // ---- cross-wave combine + MSE + fused finalize ----
#pragma unroll
  for (int rg = 0; rg < 16; rg++) {
    const int row = (rg & 3) + 8 * (rg >> 2) + 4 * lh;
    float Ls = halfSum(L2a[rg]);
    float Ts = halfSum(tpa[rg]);
    if (l31 == 0) { Lp2[w][row] = Ls; Tp2[w][row] = Ts; }
  }
  __syncthreads();
  if (w == 0) {
    float local = 0.f;
    if (l < 32) {
      float Lv = Lp2[0][l] + Lp2[1][l];
      float Tv = Tp2[0][l] + Tp2[1][l];
      float pred = Tv / Lv;
      float tt = steps[i * T_ + t0 + l];
      float d = pred - tt;
      local = d * d;
    }
    local = waveSum(local);
    if (l == 0) {
      atomicAdd(loss_acc, local);
      __threadfence();
      unsigned old = atomicAdd(cnt, 1u);
      if (old == (unsigned)(gridDim.x - 1)) {
        float v = atomicAdd(loss_acc, 0.0f);   // device-scope atomic read
        out[0] = v * (1.0f / (float)(NPAIR * T_));
      }
    }
  }
}

extern "C" void kernel_launch(void* const* d_in, const int* in_sizes, int n_in,
                              void* d_out, int out_size, void* d_ws, size_t ws_size,
                              hipStream_t stream) {
  const float* embs = (const float*)d_in[0];
  const int* frame_idxs = (const int*)d_in[1];
  const int* video_len = (const int*)d_in[2];
  float* out = (float*)d_out;

  char* ws = (char*)d_ws;
  float* acc = (float*)ws;                                     // @0
  unsigned* cnt = (unsigned*)(ws + 512);                       // @512
  float* ns = (float*)(ws + 1024);                             // 8192 f32
  float* steps = (float*)(ws + 1024 + 32768);                  // 8192 f32
  unsigned short* ebfF = (unsigned short*)(ws + 1024 + 65536); // 2 MB frag layout
  unsigned short* ebfT = ebfF + (size_t)8 * BATCH_STRIDE;      // 2 MB transposed frag

  convert_kernel<<<dim3(256), dim3(256), 0, stream>>>(embs, frame_idxs, video_len,
                                                      ebfF, ebfT, ns, steps, acc, cnt);
  tcc_main<<<dim3(NPAIR * 32), dim3(128), 0, stream>>>(ebfF, ebfT, ns, steps, acc, cnt, out);
}

// Round 6
// 158.679 us; speedup vs baseline: 1.7792x; 1.1421x over previous
//
#include <hip/hip_runtime.h>

// B=8, T=1024, D=128, TEMP=0.1, WEIGHT=1.0. 56 ordered pairs (i,j), i!=j.
// z1[t,s] = DOTSCALE*(e1_t . e2_s) - ns[s], ns = |e2_s|^2*(1/12.8)*log2e (row-const dropped)
// p = exp2(z1); nn_t = sum p*e2_s / sum p
// z2[t,s] = DOTSCALE*(nn_t . e1_s) - ns_i[s]; pred = sum exp2(z2)*sp_s / sum exp2(z2)
// loss = mean (pred - sp_t)^2.  No max-subtraction: z provably in [-40,+15].
//
// R6: R3 structure (64-thr blocks, grid 1792, 32x32x16 MFMA, no hot-loop barriers)
// + BATCHED B-fragment loads. R3/R5 were load-latency-serialized: compiler sank
// each global_load to just before its MFMA in the accumulate chain -> ~265 cyc
// stall per load, 8475 cyc/s-tile (measured = 32 loads x L2 latency). Fix:
// load 8-chunk batches into register arrays, pin with sched_barrier(0) regions
// so batches issue together and latency amortizes under MFMA/exp compute.

#define T_ 1024
#define D_ 128
#define NPAIR 56
#define DOTSCALE 0.22542110013890052f // (2/12.8)*log2(e)
#define NSCALE 0.11271055006945026f   // (1/12.8)*log2(e)

typedef short short8 __attribute__((ext_vector_type(8)));
typedef unsigned short u16x8 __attribute__((ext_vector_type(8)));
typedef float f32x16 __attribute__((ext_vector_type(16)));

#define BATCH_STRIDE 131072  // shorts per batch in frag layouts (256 chunks * 512)

__device__ __forceinline__ unsigned short f2bf(float f) {
  unsigned u = __float_as_uint(f);
  u += 0x7fff + ((u >> 16) & 1);  // RNE
  return (unsigned short)(u >> 16);
}

__device__ __forceinline__ float waveSum(float v) {
#pragma unroll
  for (int k = 32; k >= 1; k >>= 1) v += __shfl_xor(v, k, 64);
  return v;
}
__device__ __forceinline__ float halfSum(float v) {  // sum within each 32-lane half
  v += __shfl_xor(v, 1, 64); v += __shfl_xor(v, 2, 64);
  v += __shfl_xor(v, 4, 64); v += __shfl_xor(v, 8, 64);
  v += __shfl_xor(v, 16, 64);
  return v;
}

// ---- fused: fp32 -> bf16 frag layouts + norms + steps + ws init ----
// fragA (row-frag): chunk c = (t>>5)*8 + (d>>4); lane = ((d>>3)&1)*32 + (t&31); elem = d&7
// fragT (V^T frag): chunk c = (d>>5)*64 + (t>>4); lane = ((t>>3)&1)*32 + (d&31); elem = t&7
__global__ __launch_bounds__(256) void convert_kernel(
    const float* __restrict__ embs, const int* __restrict__ fi,
    const int* __restrict__ vl, unsigned short* __restrict__ ebfF,
    unsigned short* __restrict__ ebfT, float* __restrict__ ns,
    float* __restrict__ steps, float* __restrict__ acc,
    unsigned* __restrict__ cnt) {
  __shared__ unsigned short tileS[32 * 136];
  __shared__ float psum[32][8];
  const int b = blockIdx.x >> 5;
  const int t0 = (blockIdx.x & 31) * 32;
  const int tid = threadIdx.x;
  const int row = tid >> 3, seg = tid & 7;

  if (blockIdx.x == 0 && tid == 0) { acc[0] = 0.f; cnt[0] = 0u; }

  const float* src = embs + (size_t)(b * T_ + t0 + row) * D_ + seg * 16;
  float4 g[4];
#pragma unroll
  for (int k = 0; k < 4; k++) g[k] = ((const float4*)src)[k];
  float s = 0.f;
  unsigned short v[16];
#pragma unroll
  for (int k = 0; k < 4; k++) {
    s += g[k].x * g[k].x + g[k].y * g[k].y + g[k].z * g[k].z + g[k].w * g[k].w;
    v[k * 4 + 0] = f2bf(g[k].x); v[k * 4 + 1] = f2bf(g[k].y);
    v[k * 4 + 2] = f2bf(g[k].z); v[k * 4 + 3] = f2bf(g[k].w);
  }
  psum[row][seg] = s;

  unsigned short* dstA = ebfF + (size_t)b * BATCH_STRIDE + (size_t)((t0 >> 5) * 8 + seg) * 512;
  *(u16x8*)(dstA + row * 8) = *(const u16x8*)&v[0];
  *(u16x8*)(dstA + (32 + row) * 8) = *(const u16x8*)&v[8];

  *(u16x8*)&tileS[row * 136 + seg * 16] = *(const u16x8*)&v[0];
  *(u16x8*)&tileS[row * 136 + seg * 16 + 8] = *(const u16x8*)&v[8];
  __syncthreads();

  if (tid < 32) {
    float t = 0.f;
#pragma unroll
    for (int k = 0; k < 8; k++) t += psum[tid][k];
    int gr = b * T_ + t0 + tid;
    ns[gr] = t * NSCALE;
    steps[gr] = (float)fi[gr] / (float)vl[b];
  }

  const int c8 = tid >> 5;
  const int d0t = (c8 & 3) * 32, sc = c8 >> 2;
  const int chunk = (d0t >> 5) * 64 + (t0 >> 4) + sc;
  unsigned short* dstT = ebfT + (size_t)b * BATCH_STRIDE + (size_t)chunk * 512;
  const int dd = d0t + (tid & 31);
#pragma unroll
  for (int half = 0; half < 2; half++) {
    const int lane = half * 32 + (tid & 31);
    const int sl = sc * 16 + half * 8;
    u16x8 w;
#pragma unroll
    for (int jj = 0; jj < 8; jj++) w[jj] = tileS[(sl + jj) * 136 + dd];
    *(u16x8*)(dstT + lane * 8) = w;
  }
}

__global__ __launch_bounds__(64, 2) void tcc_main(
    const unsigned short* __restrict__ ebfF, const unsigned short* __restrict__ ebfT,
    const float* __restrict__ ns, const float* __restrict__ steps,
    float* __restrict__ loss_acc, unsigned* __restrict__ cnt,
    float* __restrict__ out) {
  __shared__ unsigned short buf[32 * 136];  // p (stride 72) / nn (stride 136), wave-private

  const int bx = blockIdx.x;
  const int pair = bx >> 5;
  const int tile = bx & 31;
  const int i = pair / 7;
  const int r = pair % 7;
  const int j = r + (r >= i ? 1 : 0);
  const int t0 = tile * 32;
  const int l = threadIdx.x;
  const int l31 = l & 31;
  const int lh = l >> 5;

  // Q A-frags: e1 rows t0..t0+31 (raw bf16; DOTSCALE applied in exp-fma)
  short8 qf[8];
  {
    const unsigned short* qb = ebfF + (size_t)i * BATCH_STRIDE + (size_t)((t0 >> 5) * 8) * 512 + l * 8;
#pragma unroll
    for (int kc = 0; kc < 8; kc++) qf[kc] = *(const short8*)(qb + kc * 512);
  }

  f32x16 o[4];
#pragma unroll
  for (int n2 = 0; n2 < 4; n2++)
#pragma unroll
    for (int z = 0; z < 16; z++) o[n2][z] = 0.f;
  float L1a[16];
#pragma unroll
  for (int z = 0; z < 16; z++) L1a[z] = 0.f;

  const unsigned short* kb1 = ebfF + (size_t)j * BATCH_STRIDE + l * 8;
  const unsigned short* vb1 = ebfT + (size_t)j * BATCH_STRIDE + l * 8;
  const float* nsj = ns + j * T_;

  // ---------------- phase 1: Q=e1, K=V=e2; batched loads, no barriers ----------------
  for (int st = 0; st < 16; st++) {
    const unsigned short* kp = kb1 + (size_t)(st * 16) * 512;
    const unsigned short* vp = vb1 + (size_t)(st * 4) * 512;
    const float ns0 = nsj[st * 64 + l31];
    const float ns1 = nsj[st * 64 + 32 + l31];

    // batch 1: K chunks {0..3, 8..11}
    short8 ka[8];
#pragma unroll
    for (int u = 0; u < 4; u++) {
      ka[u] = *(const short8*)(kp + u * 512);
      ka[4 + u] = *(const short8*)(kp + (8 + u) * 512);
    }
    __builtin_amdgcn_sched_barrier(0);

    f32x16 c0, c1;
#pragma unroll
    for (int z = 0; z < 16; z++) { c0[z] = 0.f; c1[z] = 0.f; }

    // region: batch 2 K loads {4..7, 12..15} issue under first-half QK
    short8 kb[8];
#pragma unroll
    for (int u = 0; u < 4; u++) {
      kb[u] = *(const short8*)(kp + (4 + u) * 512);
      kb[4 + u] = *(const short8*)(kp + (12 + u) * 512);
    }
#pragma unroll
    for (int kc = 0; kc < 4; kc++) {
      c0 = __builtin_amdgcn_mfma_f32_32x32x16_bf16(qf[kc], ka[kc], c0, 0, 0, 0);
      c1 = __builtin_amdgcn_mfma_f32_32x32x16_bf16(qf[kc], ka[4 + kc], c1, 0, 0, 0);
    }
    __builtin_amdgcn_sched_barrier(0);

    // region: V batch 1 (n2=0,1) issues under second-half QK
    short8 va[8];
#pragma unroll
    for (int u = 0; u < 8; u++)
      va[u] = *(const short8*)(vp + (size_t)(((u >> 2) * 64) + (u & 3)) * 512);
#pragma unroll
    for (int kc = 0; kc < 4; kc++) {
      c0 = __builtin_amdgcn_mfma_f32_32x32x16_bf16(qf[4 + kc], kb[kc], c0, 0, 0, 0);
      c1 = __builtin_amdgcn_mfma_f32_32x32x16_bf16(qf[4 + kc], kb[4 + kc], c1, 0, 0, 0);
    }
    __builtin_amdgcn_sched_barrier(0);

    // region: V batch 2 (n2=2,3) issues under exp section
    short8 vb[8];
#pragma unroll
    for (int u = 0; u < 8; u++)
      vb[u] = *(const short8*)(vp + (size_t)((((u >> 2) + 2) * 64) + (u & 3)) * 512);
#pragma unroll
    for (int rg = 0; rg < 16; rg++) {
      const int row = (rg & 3) + 8 * (rg >> 2) + 4 * lh;
      float p0 = __builtin_amdgcn_exp2f(c0[rg] * DOTSCALE - ns0);
      float p1 = __builtin_amdgcn_exp2f(c1[rg] * DOTSCALE - ns1);
      L1a[rg] += p0 + p1;
      buf[row * 72 + l31] = f2bf(p0);
      buf[row * 72 + 32 + l31] = f2bf(p1);
    }
    __builtin_amdgcn_sched_barrier(0);

    short8 pf[4];
#pragma unroll
    for (int kc2 = 0; kc2 < 4; kc2++)
      pf[kc2] = *(const short8*)(buf + l31 * 72 + kc2 * 16 + lh * 8);
#pragma unroll
    for (int n2 = 0; n2 < 2; n2++)
#pragma unroll
      for (int kc2 = 0; kc2 < 4; kc2++)
        o[n2] = __builtin_amdgcn_mfma_f32_32x32x16_bf16(pf[kc2], va[n2 * 4 + kc2], o[n2], 0, 0, 0);
#pragma unroll
    for (int n2 = 2; n2 < 4; n2++)
#pragma unroll
      for (int kc2 = 0; kc2 < 4; kc2++)
        o[n2] = __builtin_amdgcn_mfma_f32_32x32x16_bf16(pf[kc2], vb[(n2 - 2) * 4 + kc2], o[n2], 0, 0, 0);
  }

  // normalize nn -> LDS (stride 136), reload as A-frags
#pragma unroll
  for (int rg = 0; rg < 16; rg++) L1a[rg] = 1.0f / halfSum(L1a[rg]);
#pragma unroll
  for (int n2 = 0; n2 < 4; n2++)
#pragma unroll
    for (int rg = 0; rg < 16; rg++) {
      const int row = (rg & 3) + 8 * (rg >> 2) + 4 * lh;
      buf[row * 136 + n2 * 32 + l31] = f2bf(o[n2][rg] * L1a[rg]);
    }
  short8 qf2[8];
#pragma unroll
  for (int kc = 0; kc < 8; kc++)
    qf2[kc] = *(const short8*)(buf + l31 * 136 + kc * 16 + lh * 8);

  // ---------------- phase 2: Q=nn, K=e1, V=sp scalar; batched loads ----------------
  float L2a[16], tpa[16];
#pragma unroll
  for (int z = 0; z < 16; z++) { L2a[z] = 0.f; tpa[z] = 0.f; }
  const unsigned short* kb2 = ebfF + (size_t)i * BATCH_STRIDE + l * 8;
  const float* nsi = ns + i * T_;
  const float* spi = steps + i * T_;

  for (int st = 0; st < 16; st++) {
    const unsigned short* kp = kb2 + (size_t)(st * 16) * 512;
    const float ns0 = nsi[st * 64 + l31], sp0 = spi[st * 64 + l31];
    const float ns1 = nsi[st * 64 + 32 + l31], sp1 = spi[st * 64 + 32 + l31];

    short8 ka[8];
#pragma unroll
    for (int u = 0; u < 4; u++) {
      ka[u] = *(const short8*)(kp + u * 512);
      ka[4 + u] = *(const short8*)(kp + (8 + u) * 512);
    }
    __builtin_amdgcn_sched_barrier(0);

    f32x16 c0, c1;
#pragma unroll
    for (int z = 0; z < 16; z++) { c0[z] = 0.f; c1[z] = 0.f; }

    short8 kb[8];
#pragma unroll
    for (int u = 0; u < 4; u++) {
      kb[u] = *(const short8*)(kp + (4 + u) * 512);
      kb[4 + u] = *(const short8*)(kp + (12 + u) * 512);
    }
#pragma unroll
    for (int kc = 0; kc < 4; kc++) {
      c0 = __builtin_amdgcn_mfma_f32_32x32x16_bf16(qf2[kc], ka[kc], c0, 0, 0, 0);
      c1 = __builtin_amdgcn_mfma_f32_32x32x16_bf16(qf2[kc], ka[4 + kc], c1, 0, 0, 0);
    }
    __builtin_amdgcn_sched_barrier(0);
#pragma unroll
    for (int kc = 0; kc < 4; kc++) {
      c0 = __builtin_amdgcn_mfma_f32_32x32x16_bf16(qf2[4 + kc], kb[kc], c0, 0, 0, 0);
      c1 = __builtin_amdgcn_mfma_f32_32x32x16_bf16(qf2[4 + kc], kb[4 + kc], c1, 0, 0, 0);
    }
    __builtin_amdgcn_sched_barrier(0);
#pragma unroll
    for (int rg = 0; rg < 16; rg++) {
      float p0 = __builtin_amdgcn_exp2f(c0[rg] * DOTSCALE - ns0);
      float p1 = __builtin_amdgcn_exp2f(c1[rg] * DOTSCALE - ns1);
      L2a[rg] += p0 + p1;
      tpa[rg] += p0 * sp0 + p1 * sp1;
    }
  }

  // epilogue: reduce, MSE, one atomic per wave; fused finalize via last-block counter
  float local = 0.f;
#pragma unroll
  for (int rg = 0; rg < 16; rg++) {
    float Lv = halfSum(L2a[rg]);
    float Tv = halfSum(tpa[rg]);
    const int row = (rg & 3) + 8 * (rg >> 2) + 4 * lh;
    float pred = Tv / Lv;
    float tt = steps[i * T_ + t0 + row];
    float d = pred - tt;
    local += d * d;
  }
  if (l31 != 0) local = 0.f;
  local = waveSum(local);
  if (l == 0) {
    atomicAdd(loss_acc, local);
    __threadfence();
    unsigned old = atomicAdd(cnt, 1u);
    if (old == (unsigned)(gridDim.x - 1)) {
      float v = atomicAdd(loss_acc, 0.0f);   // device-scope atomic read
      out[0] = v * (1.0f / (float)(NPAIR * T_));
    }
  }
}

extern "C" void kernel_launch(void* const* d_in, const int* in_sizes, int n_in,
                              void* d_out, int out_size, void* d_ws, size_t ws_size,
                              hipStream_t stream) {
  const float* embs = (const float*)d_in[0];
  const int* frame_idxs = (const int*)d_in[1];
  const int* video_len = (const int*)d_in[2];
  float* out = (float*)d_out;

  char* ws = (char*)d_ws;
  float* acc = (float*)ws;                                     // @0
  unsigned* cnt = (unsigned*)(ws + 512);                       // @512
  float* ns = (float*)(ws + 1024);                             // 8192 f32
  float* steps = (float*)(ws + 1024 + 32768);                  // 8192 f32
  unsigned short* ebfF = (unsigned short*)(ws + 1024 + 65536); // 2 MB frag layout
  unsigned short* ebfT = ebfF + (size_t)8 * BATCH_STRIDE;      // 2 MB transposed frag

  convert_kernel<<<dim3(256), dim3(256), 0, stream>>>(embs, frame_idxs, video_len,
                                                      ebfF, ebfT, ns, steps, acc, cnt);
  tcc_main<<<dim3(NPAIR * 32), dim3(64), 0, stream>>>(ebfF, ebfT, ns, steps, acc, cnt, out);
}

// Round 7
// 148.642 us; speedup vs baseline: 1.8993x; 1.0675x over previous
//
#include <hip/hip_runtime.h>

// B=8, T=1024, D=128, TEMP=0.1, WEIGHT=1.0. 56 ordered pairs (i,j), i!=j.
// z1[t,s] = DOTSCALE*(e1_t . e2_s) - ns[s], ns = |e2_s|^2*(1/12.8)*log2e (row-const dropped)
// p = exp2(z1); nn_t = sum p*e2_s / sum p
// z2[t,s] = DOTSCALE*(nn_t . e1_s) - ns_i[s]; pred = sum exp2(z2)*sp_s / sum exp2(z2)
// loss = mean (pred - sp_t)^2.  No max-subtraction: z provably in [-40,+15].
//
// R7: 4-wave blocks share K/V tiles staged in LDS via global_load_lds (width 16),
// double-buffered, s-tile 32. Raises intensity to 128 FLOP per L2 byte (was 32,
// R6 was per-CU L2-delivery-bound at ~29 B/cyc). Each wave owns 32 t-rows; all
// softmax state stays within-wave (no cross-wave combines). Grid 56*8=448,
// 2 blocks/CU (LDS 65KB), launch_bounds(256,2) so no scratch spill (R4 lesson).

#define T_ 1024
#define D_ 128
#define NPAIR 56
#define DOTSCALE 0.22542110013890052f // (2/12.8)*log2(e)
#define NSCALE 0.11271055006945026f   // (1/12.8)*log2(e)

typedef short short8 __attribute__((ext_vector_type(8)));
typedef unsigned short u16x8 __attribute__((ext_vector_type(8)));
typedef float f32x16 __attribute__((ext_vector_type(16)));

#define BATCH_STRIDE 131072  // shorts per batch in frag layouts (256 chunks * 512)

__device__ __forceinline__ unsigned short f2bf(float f) {
  unsigned u = __float_as_uint(f);
  u += 0x7fff + ((u >> 16) & 1);  // RNE
  return (unsigned short)(u >> 16);
}

__device__ __forceinline__ float waveSum(float v) {
#pragma unroll
  for (int k = 32; k >= 1; k >>= 1) v += __shfl_xor(v, k, 64);
  return v;
}
__device__ __forceinline__ float halfSum(float v) {  // sum within each 32-lane half
  v += __shfl_xor(v, 1, 64); v += __shfl_xor(v, 2, 64);
  v += __shfl_xor(v, 4, 64); v += __shfl_xor(v, 8, 64);
  v += __shfl_xor(v, 16, 64);
  return v;
}

// async DMA one 512-short chunk (1024 B): per-lane 16 B global gather ->
// wave-uniform LDS base + lane*16 (global_load_lds_dwordx4)
__device__ __forceinline__ void stage1k(const unsigned short* g, unsigned short* l, int lane) {
  __builtin_amdgcn_global_load_lds(
      (const __attribute__((address_space(1))) unsigned int*)(g + lane * 8),
      (__attribute__((address_space(3))) unsigned int*)l, 16, 0, 0);
}

// ---- fused: fp32 -> bf16 frag layouts + norms + steps + ws init ----
// fragA (row-frag): chunk c = (t>>5)*8 + (d>>4); lane = ((d>>3)&1)*32 + (t&31); elem = d&7
// fragT (V^T frag): chunk c = (d>>5)*64 + (t>>4); lane = ((t>>3)&1)*32 + (d&31); elem = t&7
__global__ __launch_bounds__(256) void convert_kernel(
    const float* __restrict__ embs, const int* __restrict__ fi,
    const int* __restrict__ vl, unsigned short* __restrict__ ebfF,
    unsigned short* __restrict__ ebfT, float* __restrict__ ns,
    float* __restrict__ steps, float* __restrict__ acc,
    unsigned* __restrict__ cnt) {
  __shared__ unsigned short tileS[32 * 136];
  __shared__ float psum[32][8];
  const int b = blockIdx.x >> 5;
  const int t0 = (blockIdx.x & 31) * 32;
  const int tid = threadIdx.x;
  const int row = tid >> 3, seg = tid & 7;

  if (blockIdx.x == 0 && tid == 0) { acc[0] = 0.f; cnt[0] = 0u; }

  const float* src = embs + (size_t)(b * T_ + t0 + row) * D_ + seg * 16;
  float4 g[4];
#pragma unroll
  for (int k = 0; k < 4; k++) g[k] = ((const float4*)src)[k];
  float s = 0.f;
  unsigned short v[16];
#pragma unroll
  for (int k = 0; k < 4; k++) {
    s += g[k].x * g[k].x + g[k].y * g[k].y + g[k].z * g[k].z + g[k].w * g[k].w;
    v[k * 4 + 0] = f2bf(g[k].x); v[k * 4 + 1] = f2bf(g[k].y);
    v[k * 4 + 2] = f2bf(g[k].z); v[k * 4 + 3] = f2bf(g[k].w);
  }
  psum[row][seg] = s;

  unsigned short* dstA = ebfF + (size_t)b * BATCH_STRIDE + (size_t)((t0 >> 5) * 8 + seg) * 512;
  *(u16x8*)(dstA + row * 8) = *(const u16x8*)&v[0];
  *(u16x8*)(dstA + (32 + row) * 8) = *(const u16x8*)&v[8];

  *(u16x8*)&tileS[row * 136 + seg * 16] = *(const u16x8*)&v[0];
  *(u16x8*)&tileS[row * 136 + seg * 16 + 8] = *(const u16x8*)&v[8];
  __syncthreads();

  if (tid < 32) {
    float t = 0.f;
#pragma unroll
    for (int k = 0; k < 8; k++) t += psum[tid][k];
    int gr = b * T_ + t0 + tid;
    ns[gr] = t * NSCALE;
    steps[gr] = (float)fi[gr] / (float)vl[b];
  }

  const int c8 = tid >> 5;
  const int d0t = (c8 & 3) * 32, sc = c8 >> 2;
  const int chunk = (d0t >> 5) * 64 + (t0 >> 4) + sc;
  unsigned short* dstT = ebfT + (size_t)b * BATCH_STRIDE + (size_t)chunk * 512;
  const int dd = d0t + (tid & 31);
#pragma unroll
  for (int half = 0; half < 2; half++) {
    const int lane = half * 32 + (tid & 31);
    const int sl = sc * 16 + half * 8;
    u16x8 w;
#pragma unroll
    for (int jj = 0; jj < 8; jj++) w[jj] = tileS[(sl + jj) * 136 + dd];
    *(u16x8*)(dstT + lane * 8) = w;
  }
}

__global__ __launch_bounds__(256, 2) void tcc_main(
    const unsigned short* __restrict__ ebfF, const unsigned short* __restrict__ ebfT,
    const float* __restrict__ ns, const float* __restrict__ steps,
    float* __restrict__ loss_acc, unsigned* __restrict__ cnt,
    float* __restrict__ out) {
  // kt: [2][4096] K dbuf | vt: [2][4096] V^T dbuf | wb: per-wave 4224 (p stride 36 / nn stride 132)
  __shared__ unsigned short smem[33280];
  __shared__ float blred[4];

  const int bx = blockIdx.x;
  const int pair = bx >> 3;
  const int tile = bx & 7;
  const int i = pair / 7;
  const int r = pair % 7;
  const int j = r + (r >= i ? 1 : 0);
  const int tid = threadIdx.x;
  const int w = tid >> 6;
  const int l = tid & 63;
  const int l31 = l & 31;
  const int lh = l >> 5;
  const int tb = tile * 128 + w * 32;   // this wave's 32 t-rows

  unsigned short* kt = smem;
  unsigned short* vt = smem + 8192;
  unsigned short* wb = smem + 16384 + w * 4224;

  const unsigned short* eFi = ebfF + (size_t)i * BATCH_STRIDE;
  const unsigned short* eFj = ebfF + (size_t)j * BATCH_STRIDE;
  const unsigned short* eTj = ebfT + (size_t)j * BATCH_STRIDE;

  // Q A-frags: e1 rows tb..tb+31 (m = l31, k-half = lh)
  short8 qf[8];
  {
    const unsigned short* qb = eFi + (size_t)((tb >> 5) * 8) * 512 + l * 8;
#pragma unroll
    for (int kc = 0; kc < 8; kc++) qf[kc] = *(const short8*)(qb + kc * 512);
  }

  f32x16 o[4];
#pragma unroll
  for (int n2 = 0; n2 < 4; n2++)
#pragma unroll
    for (int z = 0; z < 16; z++) o[n2][z] = 0.f;
  float L1a[16];
#pragma unroll
  for (int z = 0; z < 16; z++) L1a[z] = 0.f;

  const float* nsj = ns + j * T_;

  // ---------------- phase 1: Q=e1, K=V=e2; s-tile 32, LDS dbuf ----------------
  // prologue: stage tile 0 (wave w stages K chunks 2w,2w+1 and V chunks db=w,u=0..1)
  stage1k(eFj + (size_t)(w * 2) * 512, kt + (w * 2) * 512, l);
  stage1k(eFj + (size_t)(w * 2 + 1) * 512, kt + (w * 2 + 1) * 512, l);
  stage1k(eTj + (size_t)(w * 64) * 512, vt + (w * 2) * 512, l);
  stage1k(eTj + (size_t)(w * 64 + 1) * 512, vt + (w * 2 + 1) * 512, l);
  __syncthreads();

  for (int st = 0; st < 32; st++) {
    const int cur = st & 1, nxt = cur ^ 1;
    if (st < 31) {
      const int s1 = st + 1;
      stage1k(eFj + (size_t)(s1 * 8 + w * 2) * 512, kt + nxt * 4096 + (w * 2) * 512, l);
      stage1k(eFj + (size_t)(s1 * 8 + w * 2 + 1) * 512, kt + nxt * 4096 + (w * 2 + 1) * 512, l);
      stage1k(eTj + (size_t)(w * 64 + s1 * 2) * 512, vt + nxt * 4096 + (w * 2) * 512, l);
      stage1k(eTj + (size_t)(w * 64 + s1 * 2 + 1) * 512, vt + nxt * 4096 + (w * 2 + 1) * 512, l);
    }
    // QK: one 32-col n-block, K=128 over 8 chunks
    f32x16 c0;
#pragma unroll
    for (int z = 0; z < 16; z++) c0[z] = 0.f;
    const unsigned short* kbase = kt + cur * 4096 + l * 8;
#pragma unroll
    for (int kc = 0; kc < 8; kc++)
      c0 = __builtin_amdgcn_mfma_f32_32x32x16_bf16(qf[kc], *(const short8*)(kbase + kc * 512), c0, 0, 0, 0);

    const float ns0 = nsj[st * 32 + l31];
#pragma unroll
    for (int rg = 0; rg < 16; rg++) {
      const int row = (rg & 3) + 8 * (rg >> 2) + 4 * lh;
      float p = __builtin_amdgcn_exp2f(c0[rg] * DOTSCALE - ns0);
      L1a[rg] += p;
      wb[row * 36 + l31] = f2bf(p);
    }
    // P A-frags (stride 36 = 2-way-free), then PV over 4 d-blocks
    short8 pf0 = *(const short8*)(wb + l31 * 36 + lh * 8);
    short8 pf1 = *(const short8*)(wb + l31 * 36 + 16 + lh * 8);
    const unsigned short* vbase = vt + cur * 4096 + l * 8;
#pragma unroll
    for (int n2 = 0; n2 < 4; n2++) {
      o[n2] = __builtin_amdgcn_mfma_f32_32x32x16_bf16(pf0, *(const short8*)(vbase + (n2 * 2) * 512), o[n2], 0, 0, 0);
      o[n2] = __builtin_amdgcn_mfma_f32_32x32x16_bf16(pf1, *(const short8*)(vbase + (n2 * 2 + 1) * 512), o[n2], 0, 0, 0);
    }
    __syncthreads();   // staging(st+1) drained + all waves done with cur
  }

  // ---- interphase: normalize nn, within-wave C->A transpose (stride 132) ----
#pragma unroll
  for (int rg = 0; rg < 16; rg++) L1a[rg] = 1.0f / halfSum(L1a[rg]);
#pragma unroll
  for (int n2 = 0; n2 < 4; n2++)
#pragma unroll
    for (int rg = 0; rg < 16; rg++) {
      const int row = (rg & 3) + 8 * (rg >> 2) + 4 * lh;
      wb[row * 132 + n2 * 32 + l31] = f2bf(o[n2][rg] * L1a[rg]);
    }
  short8 qf2[8];
#pragma unroll
  for (int kc = 0; kc < 8; kc++)
    qf2[kc] = *(const short8*)(wb + l31 * 132 + kc * 16 + lh * 8);

  // ---------------- phase 2: Q=nn, K=e1, V=sp scalar; s-tile 32, K-only dbuf ----------------
  float L2a[16], tpa[16];
#pragma unroll
  for (int z = 0; z < 16; z++) { L2a[z] = 0.f; tpa[z] = 0.f; }
  const float* nsi = ns + i * T_;
  const float* spi = steps + i * T_;

  stage1k(eFi + (size_t)(w * 2) * 512, kt + (w * 2) * 512, l);
  stage1k(eFi + (size_t)(w * 2 + 1) * 512, kt + (w * 2 + 1) * 512, l);
  __syncthreads();

  for (int st = 0; st < 32; st++) {
    const int cur = st & 1, nxt = cur ^ 1;
    if (st < 31) {
      const int s1 = st + 1;
      stage1k(eFi + (size_t)(s1 * 8 + w * 2) * 512, kt + nxt * 4096 + (w * 2) * 512, l);
      stage1k(eFi + (size_t)(s1 * 8 + w * 2 + 1) * 512, kt + nxt * 4096 + (w * 2 + 1) * 512, l);
    }
    f32x16 c0;
#pragma unroll
    for (int z = 0; z < 16; z++) c0[z] = 0.f;
    const unsigned short* kbase = kt + cur * 4096 + l * 8;
#pragma unroll
    for (int kc = 0; kc < 8; kc++)
      c0 = __builtin_amdgcn_mfma_f32_32x32x16_bf16(qf2[kc], *(const short8*)(kbase + kc * 512), c0, 0, 0, 0);

    const float ns0 = nsi[st * 32 + l31], sp0 = spi[st * 32 + l31];
#pragma unroll
    for (int rg = 0; rg < 16; rg++) {
      float p = __builtin_amdgcn_exp2f(c0[rg] * DOTSCALE - ns0);
      L2a[rg] += p;
      tpa[rg] += p * sp0;
    }
    __syncthreads();
  }

  // ---- epilogue: per-row combine, MSE, block reduce, fused finalize ----
  float local = 0.f;
#pragma unroll
  for (int rg = 0; rg < 16; rg++) {
    float Lv = halfSum(L2a[rg]);
    float Tv = halfSum(tpa[rg]);
    const int row = (rg & 3) + 8 * (rg >> 2) + 4 * lh;
    float pred = Tv / Lv;
    float tt = steps[i * T_ + tb + row];
    float d = pred - tt;
    local += d * d;
  }
  if (l31 != 0) local = 0.f;
  local = waveSum(local);
  if (l == 0) blred[w] = local;
  __syncthreads();
  if (tid == 0) {
    atomicAdd(loss_acc, blred[0] + blred[1] + blred[2] + blred[3]);
    __threadfence();
    unsigned old = atomicAdd(cnt, 1u);
    if (old == (unsigned)(gridDim.x - 1)) {
      float v = atomicAdd(loss_acc, 0.0f);   // device-scope atomic read
      out[0] = v * (1.0f / (float)(NPAIR * T_));
    }
  }
}

extern "C" void kernel_launch(void* const* d_in, const int* in_sizes, int n_in,
                              void* d_out, int out_size, void* d_ws, size_t ws_size,
                              hipStream_t stream) {
  const float* embs = (const float*)d_in[0];
  const int* frame_idxs = (const int*)d_in[1];
  const int* video_len = (const int*)d_in[2];
  float* out = (float*)d_out;

  char* ws = (char*)d_ws;
  float* acc = (float*)ws;                                     // @0
  unsigned* cnt = (unsigned*)(ws + 512);                       // @512
  float* ns = (float*)(ws + 1024);                             // 8192 f32
  float* steps = (float*)(ws + 1024 + 32768);                  // 8192 f32
  unsigned short* ebfF = (unsigned short*)(ws + 1024 + 65536); // 2 MB frag layout
  unsigned short* ebfT = ebfF + (size_t)8 * BATCH_STRIDE;      // 2 MB transposed frag

  convert_kernel<<<dim3(256), dim3(256), 0, stream>>>(embs, frame_idxs, video_len,
                                                      ebfF, ebfT, ns, steps, acc, cnt);
  tcc_main<<<dim3(NPAIR * 8), dim3(256), 0, stream>>>(ebfF, ebfT, ns, steps, acc, cnt, out);
}

// Round 8
// 142.698 us; speedup vs baseline: 1.9784x; 1.0417x over previous
//
#include <hip/hip_runtime.h>
#include <hip/hip_bf16.h>

// B=8, T=1024, D=128, TEMP=0.1, WEIGHT=1.0. 56 ordered pairs (i,j), i!=j.
// p[t,s] = exp2(dot*DOTSCALE - ns[s]) = p~[t,s] * g[s],  p~ = exp2(dot*DOTSCALE),
// g[s] = exp2(-|e_s|^2*NSCALE)  (row-const dropped; softmax-invariant).
// nn_t = (sum_s p~ * V'[s])/L,  V' = g-scaled e2 (precomputed),  L = sum_s p~*g.
// phase2: pred_t = (sum_s p~2*g2*sp)/(sum_s p~2*g2) via 2-row [g; g*sp] MFMA.
// loss = mean (pred - sp_t)^2.
//
// R8: transposed-S scheme. S^T = K*Q^T (A=K frags, B=Q frags — fragA layout is
// a valid B layout with n=t). P~^T lands in C layout where lanes l,l^32 hold the
// SAME column t with complementary s rows -> C->B-operand transform is 4
// shfl_xor(32) + cndmasks. NO LDS round-trip for P or nn. L/tp via one extra
// MFMA with a [g; g*sp] 2-row A operand. LDS = K/V'/gsp dbuf only (36 KB) ->
// 4 blocks/CU; 2-wave blocks, grid 896, barriers staggered across blocks.

#define T_ 1024
#define D_ 128
#define NPAIR 56
#define DOTSCALE 0.22542110013890052f // (2/12.8)*log2(e)
#define NSCALE 0.11271055006945026f   // (1/12.8)*log2(e)

typedef short short8 __attribute__((ext_vector_type(8)));
typedef unsigned short u16x8 __attribute__((ext_vector_type(8)));
typedef float f32x16 __attribute__((ext_vector_type(16)));

#define BATCH_STRIDE 131072  // shorts per batch in ebfF/ebfT (256 chunks * 512)
#define GSP_STRIDE 32768     // shorts per batch in gspF (64 chunks * 512)

__device__ __forceinline__ unsigned short f2bf(float f) {
  unsigned u = __float_as_uint(f);
  u += 0x7fff + ((u >> 16) & 1);  // RNE
  return (unsigned short)(u >> 16);
}
__device__ __forceinline__ float bf2f(unsigned short v) {
  return __uint_as_float(((unsigned)v) << 16);
}
__device__ __forceinline__ unsigned packbf(float a, float b) {
  __hip_bfloat162 h = __float22bfloat162_rn(float2{a, b});
  unsigned u; __builtin_memcpy(&u, &h, 4); return u;
}
__device__ __forceinline__ short8 mk8(unsigned a, unsigned b, unsigned c, unsigned d) {
  union { unsigned u[4]; short8 s; } x;
  x.u[0] = a; x.u[1] = b; x.u[2] = c; x.u[3] = d; return x.s;
}
__device__ __forceinline__ float waveSum(float v) {
#pragma unroll
  for (int k = 32; k >= 1; k >>= 1) v += __shfl_xor(v, k, 64);
  return v;
}

// async DMA one 512-short chunk (1024 B): wave-uniform LDS base + lane*16
__device__ __forceinline__ void stage1k(const unsigned short* g, unsigned short* l, int lane) {
  __builtin_amdgcn_global_load_lds(
      (const __attribute__((address_space(1))) unsigned int*)(g + lane * 8),
      (__attribute__((address_space(3))) unsigned int*)l, 16, 0, 0);
}

// C-layout (col=lane&31, row=(rg&3)+8*(rg>>2)+4*lh) -> B-operand chunks for a
// 32-wide k-range. Input: 8 packed dwords d[k]=(v[2k],v[2k+1]). Output 2 chunks.
__device__ __forceinline__ void c2b(const unsigned* d, int lh, short8* b0, short8* b1) {
  unsigned s0 = lh ? d[0] : d[2];
  unsigned s1 = lh ? d[1] : d[3];
  unsigned s2 = lh ? d[4] : d[6];
  unsigned s3 = lh ? d[5] : d[7];
  unsigned r0 = (unsigned)__shfl_xor((int)s0, 32, 64);
  unsigned r1 = (unsigned)__shfl_xor((int)s1, 32, 64);
  unsigned r2 = (unsigned)__shfl_xor((int)s2, 32, 64);
  unsigned r3 = (unsigned)__shfl_xor((int)s3, 32, 64);
  *b0 = (lh == 0) ? mk8(d[0], d[1], r0, r1) : mk8(r0, r1, d[2], d[3]);
  *b1 = (lh == 0) ? mk8(d[4], d[5], r2, r3) : mk8(r2, r3, d[6], d[7]);
}

// ---- convert: fp32 -> bf16 fragA (ebfF), g-scaled fragT (ebfT), gsp A-frags,
//      steps, ws init ----
__global__ __launch_bounds__(256) void convert_kernel(
    const float* __restrict__ embs, const int* __restrict__ fi,
    const int* __restrict__ vl, unsigned short* __restrict__ ebfF,
    unsigned short* __restrict__ ebfT, unsigned short* __restrict__ gspF,
    float* __restrict__ steps, float* __restrict__ acc, unsigned* __restrict__ cnt) {
  __shared__ unsigned short tileS[32 * 136];
  __shared__ float psum[32][8];
  __shared__ float g_sh[32], sp_sh[32];
  const int b = blockIdx.x >> 5;
  const int t0 = (blockIdx.x & 31) * 32;
  const int tid = threadIdx.x;
  const int row = tid >> 3, seg = tid & 7;

  if (blockIdx.x == 0 && tid == 0) { acc[0] = 0.f; cnt[0] = 0u; }

  const float* src = embs + (size_t)(b * T_ + t0 + row) * D_ + seg * 16;
  float4 g[4];
#pragma unroll
  for (int k = 0; k < 4; k++) g[k] = ((const float4*)src)[k];
  float s = 0.f;
  unsigned short v[16];
#pragma unroll
  for (int k = 0; k < 4; k++) {
    s += g[k].x * g[k].x + g[k].y * g[k].y + g[k].z * g[k].z + g[k].w * g[k].w;
    v[k * 4 + 0] = f2bf(g[k].x); v[k * 4 + 1] = f2bf(g[k].y);
    v[k * 4 + 2] = f2bf(g[k].z); v[k * 4 + 3] = f2bf(g[k].w);
  }
  psum[row][seg] = s;

  // fragA store (unscaled)
  unsigned short* dstA = ebfF + (size_t)b * BATCH_STRIDE + (size_t)((t0 >> 5) * 8 + seg) * 512;
  *(u16x8*)(dstA + row * 8) = *(const u16x8*)&v[0];
  *(u16x8*)(dstA + (32 + row) * 8) = *(const u16x8*)&v[8];

  *(u16x8*)&tileS[row * 136 + seg * 16] = *(const u16x8*)&v[0];
  *(u16x8*)&tileS[row * 136 + seg * 16 + 8] = *(const u16x8*)&v[8];
  __syncthreads();

  if (tid < 32) {
    float t = 0.f;
#pragma unroll
    for (int k = 0; k < 8; k++) t += psum[tid][k];
    int gr = b * T_ + t0 + tid;
    float sp = (float)fi[gr] / (float)vl[b];
    steps[gr] = sp;
    sp_sh[tid] = sp;
    g_sh[tid] = __builtin_amdgcn_exp2f(-t * NSCALE);
  }
  __syncthreads();

  // fragT store: V' = g-scaled, transposed. chunk c=(d>>5)*64+(t>>4)
  const int c8 = tid >> 5;
  const int d0t = (c8 & 3) * 32, sc = c8 >> 2;
  const int chunk = (d0t >> 5) * 64 + (t0 >> 4) + sc;
  unsigned short* dstT = ebfT + (size_t)b * BATCH_STRIDE + (size_t)chunk * 512;
  const int dd = d0t + (tid & 31);
#pragma unroll
  for (int half = 0; half < 2; half++) {
    const int lane = half * 32 + (tid & 31);
    const int sl = sc * 16 + half * 8;
    u16x8 w;
#pragma unroll
    for (int jj = 0; jj < 8; jj++)
      w[jj] = f2bf(bf2f(tileS[(sl + jj) * 136 + dd]) * g_sh[sl + jj]);
    *(u16x8*)(dstT + lane * 8) = w;
  }

  // gsp A-frags: rows m=0 -> g, m=1 -> g*sp, rest 0. 2 chunks per block.
  for (int idx = tid; idx < 1024; idx += 256) {
    int cchunk = idx >> 9, within = idx & 511;
    int lane = within >> 3, e = within & 7;
    int m = lane & 31, kh = lane >> 5;
    int sl = cchunk * 16 + kh * 8 + e;
    unsigned short val = 0;
    if (m == 0) val = f2bf(g_sh[sl]);
    else if (m == 1) val = f2bf(g_sh[sl] * sp_sh[sl]);
    gspF[(size_t)b * GSP_STRIDE + (size_t)((t0 >> 4) + cchunk) * 512 + within] = val;
  }
}

__global__ __launch_bounds__(128, 2) void tcc_main(
    const unsigned short* __restrict__ ebfF, const unsigned short* __restrict__ ebfT,
    const unsigned short* __restrict__ gspF, const float* __restrict__ steps,
    float* __restrict__ loss_acc, unsigned* __restrict__ cnt, float* __restrict__ out) {
  // kt[2][4096] | vt[2][4096] | gt[2][1024]  = 18432 shorts = 36 KB
  __shared__ unsigned short smem[18432];
  __shared__ float blred[2];
  unsigned short* kt = smem;
  unsigned short* vt = smem + 8192;
  unsigned short* gt = smem + 16384;

  const int bx = blockIdx.x;
  const int pair = bx >> 4;
  const int tile = bx & 15;
  const int i = pair / 7;
  const int r = pair % 7;
  const int j = r + (r >= i ? 1 : 0);
  const int tid = threadIdx.x;
  const int w = tid >> 6;
  const int l = tid & 63;
  const int l31 = l & 31;
  const int lh = l >> 5;
  const int tb = tile * 64 + w * 32;   // this wave's 32 t-rows

  const unsigned short* eFi = ebfF + (size_t)i * BATCH_STRIDE;
  const unsigned short* eFj = ebfF + (size_t)j * BATCH_STRIDE;
  const unsigned short* eTj = ebfT + (size_t)j * BATCH_STRIDE;
  const unsigned short* gFi = gspF + (size_t)i * GSP_STRIDE;
  const unsigned short* gFj = gspF + (size_t)j * GSP_STRIDE;

  // Q as B-operand: fragA of e1 rows tb..tb+31 (n=t, k=d)
  short8 qf[8];
  {
    const unsigned short* qb = eFi + (size_t)((tb >> 5) * 8) * 512 + l * 8;
#pragma unroll
    for (int kc = 0; kc < 8; kc++) qf[kc] = *(const short8*)(qb + kc * 512);
  }

  f32x16 o[4], acc5;
#pragma unroll
  for (int n2 = 0; n2 < 4; n2++)
#pragma unroll
    for (int z = 0; z < 16; z++) o[n2][z] = 0.f;
#pragma unroll
  for (int z = 0; z < 16; z++) acc5[z] = 0.f;

  // ---------------- phase 1: S^T = K*Q^T, O^T = V'^T * P~^T ----------------
  // prologue: stage s-tile 0 (wave w: K chunks 4w..4w+3, V' 4w..4w+3, gsp w)
#pragma unroll
  for (int u = 0; u < 4; u++) {
    stage1k(eFj + (size_t)(4 * w + u) * 512, kt + (4 * w + u) * 512, l);
    int n2 = 2 * w + (u >> 1), c = u & 1;
    stage1k(eTj + (size_t)(n2 * 64 + c) * 512, vt + (4 * w + u) * 512, l);
  }
  stage1k(gFj + (size_t)w * 512, gt + w * 512, l);
  __syncthreads();

  for (int st = 0; st < 32; st++) {
    const int cur = st & 1, nxt = cur ^ 1;
    if (st < 31) {
      const int s1 = st + 1;
#pragma unroll
      for (int u = 0; u < 4; u++) {
        stage1k(eFj + (size_t)(s1 * 8 + 4 * w + u) * 512, kt + nxt * 4096 + (4 * w + u) * 512, l);
        int n2 = 2 * w + (u >> 1), c = u & 1;
        stage1k(eTj + (size_t)(n2 * 64 + s1 * 2 + c) * 512, vt + nxt * 4096 + (4 * w + u) * 512, l);
      }
      stage1k(gFj + (size_t)(s1 * 2 + w) * 512, gt + nxt * 1024 + w * 512, l);
    }
    // QK^T: A=K chunks (k=d), B=qf. Two acc chains.
    const unsigned short* kbase = kt + cur * 4096 + l * 8;
    f32x16 ca, cb;
#pragma unroll
    for (int z = 0; z < 16; z++) { ca[z] = 0.f; cb[z] = 0.f; }
#pragma unroll
    for (int kc = 0; kc < 4; kc++) {
      ca = __builtin_amdgcn_mfma_f32_32x32x16_bf16(*(const short8*)(kbase + (2 * kc) * 512), qf[2 * kc], ca, 0, 0, 0);
      cb = __builtin_amdgcn_mfma_f32_32x32x16_bf16(*(const short8*)(kbase + (2 * kc + 1) * 512), qf[2 * kc + 1], cb, 0, 0, 0);
    }
    // p~ = exp2(dot*DOTSCALE); pack; C->B transform (4 shfl_xor)
    unsigned d[8];
#pragma unroll
    for (int k2 = 0; k2 < 8; k2++) {
      float pa = __builtin_amdgcn_exp2f((ca[2 * k2] + cb[2 * k2]) * DOTSCALE);
      float pb = __builtin_amdgcn_exp2f((ca[2 * k2 + 1] + cb[2 * k2 + 1]) * DOTSCALE);
      d[k2] = packbf(pa, pb);
    }
    short8 pB0, pB1;
    c2b(d, lh, &pB0, &pB1);
    // PV + gsp: A chunks k = s (2 per tile)
    const unsigned short* vbase = vt + cur * 4096 + l * 8;
    const unsigned short* gbase = gt + cur * 1024 + l * 8;
    acc5 = __builtin_amdgcn_mfma_f32_32x32x16_bf16(*(const short8*)(gbase), pB0, acc5, 0, 0, 0);
    acc5 = __builtin_amdgcn_mfma_f32_32x32x16_bf16(*(const short8*)(gbase + 512), pB1, acc5, 0, 0, 0);
#pragma unroll
    for (int n2 = 0; n2 < 4; n2++) {
      o[n2] = __builtin_amdgcn_mfma_f32_32x32x16_bf16(*(const short8*)(vbase + (n2 * 2) * 512), pB0, o[n2], 0, 0, 0);
      o[n2] = __builtin_amdgcn_mfma_f32_32x32x16_bf16(*(const short8*)(vbase + (n2 * 2 + 1) * 512), pB1, o[n2], 0, 0, 0);
    }
    __syncthreads();
  }

  // ---- interphase: nn^T = O^T / L; build phase-2 B-frags via shfl (no LDS) ----
  float Lme = acc5[0];                       // L[t] at lh=0 lanes (row 0)
  float Lo = __shfl_xor(Lme, 32, 64);
  float inv = 1.0f / (lh ? Lo : Lme);
  short8 qf2[8];
#pragma unroll
  for (int n2 = 0; n2 < 4; n2++) {
    unsigned d[8];
#pragma unroll
    for (int k2 = 0; k2 < 8; k2++)
      d[k2] = packbf(o[n2][2 * k2] * inv, o[n2][2 * k2 + 1] * inv);
    c2b(d, lh, &qf2[2 * n2], &qf2[2 * n2 + 1]);
  }

  // ---------------- phase 2: S2^T = K2 * nn^T; L2/tp via gsp MFMA ----------------
  f32x16 acc6;
#pragma unroll
  for (int z = 0; z < 16; z++) acc6[z] = 0.f;

#pragma unroll
  for (int u = 0; u < 4; u++)
    stage1k(eFi + (size_t)(4 * w + u) * 512, kt + (4 * w + u) * 512, l);
  stage1k(gFi + (size_t)w * 512, gt + w * 512, l);
  __syncthreads();

  for (int st = 0; st < 32; st++) {
    const int cur = st & 1, nxt = cur ^ 1;
    if (st < 31) {
      const int s1 = st + 1;
#pragma unroll
      for (int u = 0; u < 4; u++)
        stage1k(eFi + (size_t)(s1 * 8 + 4 * w + u) * 512, kt + nxt * 4096 + (4 * w + u) * 512, l);
      stage1k(gFi + (size_t)(s1 * 2 + w) * 512, gt + nxt * 1024 + w * 512, l);
    }
    const unsigned short* kbase = kt + cur * 4096 + l * 8;
    f32x16 ca, cb;
#pragma unroll
    for (int z = 0; z < 16; z++) { ca[z] = 0.f; cb[z] = 0.f; }
#pragma unroll
    for (int kc = 0; kc < 4; kc++) {
      ca = __builtin_amdgcn_mfma_f32_32x32x16_bf16(*(const short8*)(kbase + (2 * kc) * 512), qf2[2 * kc], ca, 0, 0, 0);
      cb = __builtin_amdgcn_mfma_f32_32x32x16_bf16(*(const short8*)(kbase + (2 * kc + 1) * 512), qf2[2 * kc + 1], cb, 0, 0, 0);
    }
    unsigned d[8];
#pragma unroll
    for (int k2 = 0; k2 < 8; k2++) {
      float pa = __builtin_amdgcn_exp2f((ca[2 * k2] + cb[2 * k2]) * DOTSCALE);
      float pb = __builtin_amdgcn_exp2f((ca[2 * k2 + 1] + cb[2 * k2 + 1]) * DOTSCALE);
      d[k2] = packbf(pa, pb);
    }
    short8 pB0, pB1;
    c2b(d, lh, &pB0, &pB1);
    const unsigned short* gbase = gt + cur * 1024 + l * 8;
    acc6 = __builtin_amdgcn_mfma_f32_32x32x16_bf16(*(const short8*)(gbase), pB0, acc6, 0, 0, 0);
    acc6 = __builtin_amdgcn_mfma_f32_32x32x16_bf16(*(const short8*)(gbase + 512), pB1, acc6, 0, 0, 0);
    __syncthreads();
  }

  // ---- epilogue: pred = tp/L2 (rows 0,1 at lh=0 lanes), MSE, fused finalize ----
  float local = 0.f;
  if (lh == 0) {
    float pred = acc6[1] / acc6[0];
    float tt = steps[i * T_ + tb + l31];
    float dd = pred - tt;
    local = dd * dd;
  }
  local = waveSum(local);
  if (l == 0) blred[w] = local;
  __syncthreads();
  if (tid == 0) {
    atomicAdd(loss_acc, blred[0] + blred[1]);
    __threadfence();
    unsigned old = atomicAdd(cnt, 1u);
    if (old == (unsigned)(gridDim.x - 1)) {
      float v = atomicAdd(loss_acc, 0.0f);   // device-scope atomic read
      out[0] = v * (1.0f / (float)(NPAIR * T_));
    }
  }
}

extern "C" void kernel_launch(void* const* d_in, const int* in_sizes, int n_in,
                              void* d_out, int out_size, void* d_ws, size_t ws_size,
                              hipStream_t stream) {
  const float* embs = (const float*)d_in[0];
  const int* frame_idxs = (const int*)d_in[1];
  const int* video_len = (const int*)d_in[2];
  float* out = (float*)d_out;

  char* ws = (char*)d_ws;
  float* acc = (float*)ws;                                      // @0
  unsigned* cnt = (unsigned*)(ws + 512);                        // @512
  float* steps = (float*)(ws + 4096);                           // 8192 f32 (32 KB)
  unsigned short* ebfF = (unsigned short*)(ws + 65536);         // 2 MB
  unsigned short* ebfT = ebfF + (size_t)8 * BATCH_STRIDE;       // 2 MB
  unsigned short* gspF = ebfT + (size_t)8 * BATCH_STRIDE;       // 512 KB

  convert_kernel<<<dim3(256), dim3(256), 0, stream>>>(embs, frame_idxs, video_len,
                                                      ebfF, ebfT, gspF, steps, acc, cnt);
  tcc_main<<<dim3(NPAIR * 16), dim3(128), 0, stream>>>(ebfF, ebfT, gspF, steps, acc, cnt, out);
}

// Round 9
// 128.740 us; speedup vs baseline: 2.1929x; 1.1084x over previous
//
#include <hip/hip_runtime.h>
#include <hip/hip_bf16.h>

// B=8, T=1024, D=128, TEMP=0.1, WEIGHT=1.0. 56 ordered pairs (i,j), i!=j.
// p~ = exp2(dot(SQDS*q, SQDS*k)) ; g[s] = exp2(-|e_s|^2*NSCALE) (row-const dropped)
// nn_t = (sum p~ V')/L, V' = g*SQDS-scaled e2, L = sum p~ g (via [g; g*sp] MFMA)
// phase2: pred = (sum p~2 g2 sp)/(sum p~2 g2);  loss = mean (pred - sp_t)^2
//
// R9: s-tile 64, 4-wave blocks (t-tile 128), grid 448 = exactly 2 blocks/CU
// (LDS 72 KB) -> 8 waves/CU in one dispatch round; iteration count halves
// (16+16 barriers). Transposed-S scheme from R8 (S^T = K*Q^T, C->B via 4
// shfl_xor(32), no P/nn LDS round-trip), L/tp via [g; g*sp] MFMA. SQDS folded
// into ebfF/ebfT so exp arg = ca+cb directly.

#define T_ 1024
#define D_ 128
#define NPAIR 56
#define NSCALE 0.11271055006945026f   // (1/12.8)*log2(e)
#define SQDS 0.474785316f             // sqrt((2/12.8)*log2(e))

typedef short short8 __attribute__((ext_vector_type(8)));
typedef unsigned short u16x8 __attribute__((ext_vector_type(8)));
typedef float f32x16 __attribute__((ext_vector_type(16)));

#define BATCH_STRIDE 131072  // shorts per batch in ebfF/ebfT (256 chunks * 512)
#define GSP_STRIDE 32768     // shorts per batch in gspF (64 chunks * 512)

__device__ __forceinline__ unsigned short f2bf(float f) {
  unsigned u = __float_as_uint(f);
  u += 0x7fff + ((u >> 16) & 1);  // RNE
  return (unsigned short)(u >> 16);
}
__device__ __forceinline__ float bf2f(unsigned short v) {
  return __uint_as_float(((unsigned)v) << 16);
}
__device__ __forceinline__ unsigned packbf(float a, float b) {
  __hip_bfloat162 h = __float22bfloat162_rn(float2{a, b});
  unsigned u; __builtin_memcpy(&u, &h, 4); return u;
}
__device__ __forceinline__ short8 mk8(unsigned a, unsigned b, unsigned c, unsigned d) {
  union { unsigned u[4]; short8 s; } x;
  x.u[0] = a; x.u[1] = b; x.u[2] = c; x.u[3] = d; return x.s;
}
__device__ __forceinline__ float waveSum(float v) {
#pragma unroll
  for (int k = 32; k >= 1; k >>= 1) v += __shfl_xor(v, k, 64);
  return v;
}

// async DMA one 512-short chunk (1024 B): wave-uniform LDS base + lane*16
__device__ __forceinline__ void stage1k(const unsigned short* g, unsigned short* l, int lane) {
  __builtin_amdgcn_global_load_lds(
      (const __attribute__((address_space(1))) unsigned int*)(g + lane * 8),
      (__attribute__((address_space(3))) unsigned int*)l, 16, 0, 0);
}

// C-layout (col=lane&31, row=(rg&3)+8*(rg>>2)+4*lh) -> B-operand chunks for a
// 32-wide k-range. Input: 8 packed dwords d[k]=(rows 2k,2k+1). Output 2 chunks.
__device__ __forceinline__ void c2b(const unsigned* d, int lh, short8* b0, short8* b1) {
  unsigned s0 = lh ? d[0] : d[2];
  unsigned s1 = lh ? d[1] : d[3];
  unsigned s2 = lh ? d[4] : d[6];
  unsigned s3 = lh ? d[5] : d[7];
  unsigned r0 = (unsigned)__shfl_xor((int)s0, 32, 64);
  unsigned r1 = (unsigned)__shfl_xor((int)s1, 32, 64);
  unsigned r2 = (unsigned)__shfl_xor((int)s2, 32, 64);
  unsigned r3 = (unsigned)__shfl_xor((int)s3, 32, 64);
  *b0 = (lh == 0) ? mk8(d[0], d[1], r0, r1) : mk8(r0, r1, d[2], d[3]);
  *b1 = (lh == 0) ? mk8(d[4], d[5], r2, r3) : mk8(r2, r3, d[6], d[7]);
}

// ---- convert: fp32 -> SQDS-scaled bf16 fragA (ebfF), g*SQDS-scaled fragT
//      (ebfT), gsp A-frags ([g; g*sp]), steps, ws init ----
__global__ __launch_bounds__(256) void convert_kernel(
    const float* __restrict__ embs, const int* __restrict__ fi,
    const int* __restrict__ vl, unsigned short* __restrict__ ebfF,
    unsigned short* __restrict__ ebfT, unsigned short* __restrict__ gspF,
    float* __restrict__ steps, float* __restrict__ acc, unsigned* __restrict__ cnt) {
  __shared__ unsigned short tileS[32 * 136];
  __shared__ float psum[32][8];
  __shared__ float g_sh[32], sp_sh[32];
  const int b = blockIdx.x >> 5;
  const int t0 = (blockIdx.x & 31) * 32;
  const int tid = threadIdx.x;
  const int row = tid >> 3, seg = tid & 7;

  if (blockIdx.x == 0 && tid == 0) { acc[0] = 0.f; cnt[0] = 0u; }

  const float* src = embs + (size_t)(b * T_ + t0 + row) * D_ + seg * 16;
  float4 g[4];
#pragma unroll
  for (int k = 0; k < 4; k++) g[k] = ((const float4*)src)[k];
  float s = 0.f;
  unsigned short v[16];
#pragma unroll
  for (int k = 0; k < 4; k++) {
    s += g[k].x * g[k].x + g[k].y * g[k].y + g[k].z * g[k].z + g[k].w * g[k].w;
    v[k * 4 + 0] = f2bf(g[k].x * SQDS); v[k * 4 + 1] = f2bf(g[k].y * SQDS);
    v[k * 4 + 2] = f2bf(g[k].z * SQDS); v[k * 4 + 3] = f2bf(g[k].w * SQDS);
  }
  psum[row][seg] = s;

  // fragA store (SQDS-scaled)
  unsigned short* dstA = ebfF + (size_t)b * BATCH_STRIDE + (size_t)((t0 >> 5) * 8 + seg) * 512;
  *(u16x8*)(dstA + row * 8) = *(const u16x8*)&v[0];
  *(u16x8*)(dstA + (32 + row) * 8) = *(const u16x8*)&v[8];

  *(u16x8*)&tileS[row * 136 + seg * 16] = *(const u16x8*)&v[0];
  *(u16x8*)&tileS[row * 136 + seg * 16 + 8] = *(const u16x8*)&v[8];
  __syncthreads();

  if (tid < 32) {
    float t = 0.f;
#pragma unroll
    for (int k = 0; k < 8; k++) t += psum[tid][k];
    int gr = b * T_ + t0 + tid;
    float sp = (float)fi[gr] / (float)vl[b];
    steps[gr] = sp;
    sp_sh[tid] = sp;
    g_sh[tid] = __builtin_amdgcn_exp2f(-t * NSCALE);
  }
  __syncthreads();

  // fragT store: V' = g-scaled (SQDS already in tileS), transposed
  const int c8 = tid >> 5;
  const int d0t = (c8 & 3) * 32, sc = c8 >> 2;
  const int chunk = (d0t >> 5) * 64 + (t0 >> 4) + sc;
  unsigned short* dstT = ebfT + (size_t)b * BATCH_STRIDE + (size_t)chunk * 512;
  const int dd = d0t + (tid & 31);
#pragma unroll
  for (int half = 0; half < 2; half++) {
    const int lane = half * 32 + (tid & 31);
    const int sl = sc * 16 + half * 8;
    u16x8 w;
#pragma unroll
    for (int jj = 0; jj < 8; jj++)
      w[jj] = f2bf(bf2f(tileS[(sl + jj) * 136 + dd]) * g_sh[sl + jj]);
    *(u16x8*)(dstT + lane * 8) = w;
  }

  // gsp A-frags: rows m=0 -> g, m=1 -> g*sp, rest 0 (unscaled)
  for (int idx = tid; idx < 1024; idx += 256) {
    int cchunk = idx >> 9, within = idx & 511;
    int lane = within >> 3, e = within & 7;
    int m = lane & 31, kh = lane >> 5;
    int sl = cchunk * 16 + kh * 8 + e;
    unsigned short val = 0;
    if (m == 0) val = f2bf(g_sh[sl]);
    else if (m == 1) val = f2bf(g_sh[sl] * sp_sh[sl]);
    gspF[(size_t)b * GSP_STRIDE + (size_t)((t0 >> 4) + cchunk) * 512 + within] = val;
  }
}

__global__ __launch_bounds__(256, 2) void tcc_main(
    const unsigned short* __restrict__ ebfF, const unsigned short* __restrict__ ebfT,
    const unsigned short* __restrict__ gspF, const float* __restrict__ steps,
    float* __restrict__ loss_acc, unsigned* __restrict__ cnt, float* __restrict__ out) {
  // kt[2][8192] | vt[2][8192] | gt[2][2048]  = 36864 shorts = 72 KB -> 2 blocks/CU
  __shared__ unsigned short smem[36864];
  __shared__ float blred[4];
  unsigned short* kt = smem;
  unsigned short* vt = smem + 16384;
  unsigned short* gt = smem + 32768;

  const int bx = blockIdx.x;
  const int pair = bx >> 3;
  const int tile = bx & 7;
  const int i = pair / 7;
  const int r = pair % 7;
  const int j = r + (r >= i ? 1 : 0);
  const int tid = threadIdx.x;
  const int w = tid >> 6;
  const int l = tid & 63;
  const int l31 = l & 31;
  const int lh = l >> 5;
  const int tb = tile * 128 + w * 32;   // this wave's 32 t-rows

  const unsigned short* eFi = ebfF + (size_t)i * BATCH_STRIDE;
  const unsigned short* eFj = ebfF + (size_t)j * BATCH_STRIDE;
  const unsigned short* eTj = ebfT + (size_t)j * BATCH_STRIDE;
  const unsigned short* gFi = gspF + (size_t)i * GSP_STRIDE;
  const unsigned short* gFj = gspF + (size_t)j * GSP_STRIDE;

  // Q as B-operand: fragA of e1 rows tb..tb+31 (n=t, k=d)
  short8 qf[8];
  {
    const unsigned short* qb = eFi + (size_t)((tb >> 5) * 8) * 512 + l * 8;
#pragma unroll
    for (int kc = 0; kc < 8; kc++) qf[kc] = *(const short8*)(qb + kc * 512);
  }

  f32x16 o[4], acc5;
#pragma unroll
  for (int n2 = 0; n2 < 4; n2++)
#pragma unroll
    for (int z = 0; z < 16; z++) o[n2][z] = 0.f;
#pragma unroll
  for (int z = 0; z < 16; z++) acc5[z] = 0.f;

  // ---------------- phase 1: s-tile 64, 16 iterations ----------------
  // K local chunk q=sb*8+kc <-> global st*16+q ; V local v=n2*4+sc <-> global
  // n2*64+st*4+sc ; g local c <-> global st*4+c. Wave w stages K q=4w..4w+3,
  // V v=4w..4w+3 (n2=w), g c=w.
#pragma unroll
  for (int u = 0; u < 4; u++) {
    stage1k(eFj + (size_t)(4 * w + u) * 512, kt + (4 * w + u) * 512, l);
    stage1k(eTj + (size_t)(w * 64 + u) * 512, vt + (4 * w + u) * 512, l);
  }
  stage1k(gFj + (size_t)w * 512, gt + w * 512, l);
  __syncthreads();

  for (int st = 0; st < 16; st++) {
    const int cur = st & 1, nxt = cur ^ 1;
    if (st < 15) {
      const int s1 = st + 1;
#pragma unroll
      for (int u = 0; u < 4; u++) {
        stage1k(eFj + (size_t)(s1 * 16 + 4 * w + u) * 512, kt + nxt * 8192 + (4 * w + u) * 512, l);
        stage1k(eTj + (size_t)(w * 64 + s1 * 4 + u) * 512, vt + nxt * 8192 + (4 * w + u) * 512, l);
      }
      stage1k(gFj + (size_t)(s1 * 4 + w) * 512, gt + nxt * 2048 + w * 512, l);
    }
    const unsigned short* kbase = kt + cur * 8192 + l * 8;
    const unsigned short* vbase = vt + cur * 8192 + l * 8;
    const unsigned short* gbase = gt + cur * 2048 + l * 8;

    short8 pB[4];
#pragma unroll
    for (int sb = 0; sb < 2; sb++) {
      f32x16 ca, cb;
#pragma unroll
      for (int z = 0; z < 16; z++) { ca[z] = 0.f; cb[z] = 0.f; }
#pragma unroll
      for (int kc = 0; kc < 4; kc++) {
        ca = __builtin_amdgcn_mfma_f32_32x32x16_bf16(*(const short8*)(kbase + (sb * 8 + 2 * kc) * 512), qf[2 * kc], ca, 0, 0, 0);
        cb = __builtin_amdgcn_mfma_f32_32x32x16_bf16(*(const short8*)(kbase + (sb * 8 + 2 * kc + 1) * 512), qf[2 * kc + 1], cb, 0, 0, 0);
      }
      unsigned d[8];
#pragma unroll
      for (int k2 = 0; k2 < 8; k2++) {
        float pa = __builtin_amdgcn_exp2f(ca[2 * k2] + cb[2 * k2]);
        float pb = __builtin_amdgcn_exp2f(ca[2 * k2 + 1] + cb[2 * k2 + 1]);
        d[k2] = packbf(pa, pb);
      }
      c2b(d, lh, &pB[2 * sb], &pB[2 * sb + 1]);
    }
#pragma unroll
    for (int c = 0; c < 4; c++)
      acc5 = __builtin_amdgcn_mfma_f32_32x32x16_bf16(*(const short8*)(gbase + c * 512), pB[c], acc5, 0, 0, 0);
#pragma unroll
    for (int n2 = 0; n2 < 4; n2++)
#pragma unroll
      for (int c = 0; c < 4; c++)
        o[n2] = __builtin_amdgcn_mfma_f32_32x32x16_bf16(*(const short8*)(vbase + (n2 * 4 + c) * 512), pB[c], o[n2], 0, 0, 0);
    __syncthreads();
  }

  // stage phase-2 tile 0 (overlaps interphase math; all waves past last read)
#pragma unroll
  for (int u = 0; u < 4; u++)
    stage1k(eFi + (size_t)(4 * w + u) * 512, kt + (4 * w + u) * 512, l);
  stage1k(gFi + (size_t)w * 512, gt + w * 512, l);

  // ---- interphase: nn^T = O^T / L; phase-2 B-frags via shfl (no LDS) ----
  float Lme = acc5[0];                       // L[t] at lh=0 lanes (row 0)
  float Lo = __shfl_xor(Lme, 32, 64);
  float inv = 1.0f / (lh ? Lo : Lme);
  short8 qf2[8];
#pragma unroll
  for (int n2 = 0; n2 < 4; n2++) {
    unsigned d[8];
#pragma unroll
    for (int k2 = 0; k2 < 8; k2++)
      d[k2] = packbf(o[n2][2 * k2] * inv, o[n2][2 * k2 + 1] * inv);
    c2b(d, lh, &qf2[2 * n2], &qf2[2 * n2 + 1]);
  }

  // ---------------- phase 2: s-tile 64, 16 iterations, K + gsp only ----------------
  f32x16 acc6;
#pragma unroll
  for (int z = 0; z < 16; z++) acc6[z] = 0.f;
  __syncthreads();

  for (int st = 0; st < 16; st++) {
    const int cur = st & 1, nxt = cur ^ 1;
    if (st < 15) {
      const int s1 = st + 1;
#pragma unroll
      for (int u = 0; u < 4; u++)
        stage1k(eFi + (size_t)(s1 * 16 + 4 * w + u) * 512, kt + nxt * 8192 + (4 * w + u) * 512, l);
      stage1k(gFi + (size_t)(s1 * 4 + w) * 512, gt + nxt * 2048 + w * 512, l);
    }
    const unsigned short* kbase = kt + cur * 8192 + l * 8;
    const unsigned short* gbase = gt + cur * 2048 + l * 8;

    short8 pB[4];
#pragma unroll
    for (int sb = 0; sb < 2; sb++) {
      f32x16 ca, cb;
#pragma unroll
      for (int z = 0; z < 16; z++) { ca[z] = 0.f; cb[z] = 0.f; }
#pragma unroll
      for (int kc = 0; kc < 4; kc++) {
        ca = __builtin_amdgcn_mfma_f32_32x32x16_bf16(*(const short8*)(kbase + (sb * 8 + 2 * kc) * 512), qf2[2 * kc], ca, 0, 0, 0);
        cb = __builtin_amdgcn_mfma_f32_32x32x16_bf16(*(const short8*)(kbase + (sb * 8 + 2 * kc + 1) * 512), qf2[2 * kc + 1], cb, 0, 0, 0);
      }
      unsigned d[8];
#pragma unroll
      for (int k2 = 0; k2 < 8; k2++) {
        float pa = __builtin_amdgcn_exp2f(ca[2 * k2] + cb[2 * k2]);
        float pb = __builtin_amdgcn_exp2f(ca[2 * k2 + 1] + cb[2 * k2 + 1]);
        d[k2] = packbf(pa, pb);
      }
      c2b(d, lh, &pB[2 * sb], &pB[2 * sb + 1]);
    }
#pragma unroll
    for (int c = 0; c < 4; c++)
      acc6 = __builtin_amdgcn_mfma_f32_32x32x16_bf16(*(const short8*)(gbase + c * 512), pB[c], acc6, 0, 0, 0);
    __syncthreads();
  }

  // ---- epilogue: pred = tp/L2 (rows 0,1 at lh=0 lanes), MSE, fused finalize ----
  float local = 0.f;
  if (lh == 0) {
    float pred = acc6[1] / acc6[0];
    float tt = steps[i * T_ + tb + l31];
    float dd = pred - tt;
    local = dd * dd;
  }
  local = waveSum(local);
  if (l == 0) blred[w] = local;
  __syncthreads();
  if (tid == 0) {
    atomicAdd(loss_acc, blred[0] + blred[1] + blred[2] + blred[3]);
    __threadfence();
    unsigned old = atomicAdd(cnt, 1u);
    if (old == (unsigned)(gridDim.x - 1)) {
      float v = atomicAdd(loss_acc, 0.0f);   // device-scope atomic read
      out[0] = v * (1.0f / (float)(NPAIR * T_));
    }
  }
}

extern "C" void kernel_launch(void* const* d_in, const int* in_sizes, int n_in,
                              void* d_out, int out_size, void* d_ws, size_t ws_size,
                              hipStream_t stream) {
  const float* embs = (const float*)d_in[0];
  const int* frame_idxs = (const int*)d_in[1];
  const int* video_len = (const int*)d_in[2];
  float* out = (float*)d_out;

  char* ws = (char*)d_ws;
  float* acc = (float*)ws;                                      // @0
  unsigned* cnt = (unsigned*)(ws + 512);                        // @512
  float* steps = (float*)(ws + 4096);                           // 8192 f32
  unsigned short* ebfF = (unsigned short*)(ws + 65536);         // 2 MB
  unsigned short* ebfT = ebfF + (size_t)8 * BATCH_STRIDE;       // 2 MB
  unsigned short* gspF = ebfT + (size_t)8 * BATCH_STRIDE;       // 512 KB

  convert_kernel<<<dim3(256), dim3(256), 0, stream>>>(embs, frame_idxs, video_len,
                                                      ebfF, ebfT, gspF, steps, acc, cnt);
  tcc_main<<<dim3(NPAIR * 8), dim3(256), 0, stream>>>(ebfF, ebfT, gspF, steps, acc, cnt, out);
}

// Round 10
// 125.898 us; speedup vs baseline: 2.2424x; 1.0226x over previous
//
#include <hip/hip_runtime.h>
#include <hip/hip_bf16.h>

// B=8, T=1024, D=128, TEMP=0.1, WEIGHT=1.0. 56 ordered pairs (i,j), i!=j.
// p~ = exp2(dot(SQDS*q, SQDS*k)) ; g[s] = exp2(-|e_s|^2*NSCALE) (row-const dropped)
// nn_t = (sum p~ V')/L, V' = g*SQDS-scaled e2, L = sum p~ g (via [g; g*sp] MFMA)
// phase2: pred = (sum p~2 g2 sp)/(sum p~2 g2);  loss = mean (pred - sp_t)^2
//
// R10 = R9 + two scheduling fixes (cross-round fit: W~2180, F~1490 cyc/iter fixed
// barrier cost):
//  1. sched_barrier(0) after the staging block pins DMA issue before compute so
//     L2->LDS completion overlaps the ~2200-cyc body (kills the vmcnt drain F).
//  2. Stage-parallel body: all 4 QK chains, then all exps, then c2b, then PV —
//     max ILP per stage so MFMA/trans/DS pipes overlap within a wave.

#define T_ 1024
#define D_ 128
#define NPAIR 56
#define NSCALE 0.11271055006945026f   // (1/12.8)*log2(e)
#define SQDS 0.474785316f             // sqrt((2/12.8)*log2(e))

typedef short short8 __attribute__((ext_vector_type(8)));
typedef unsigned short u16x8 __attribute__((ext_vector_type(8)));
typedef float f32x16 __attribute__((ext_vector_type(16)));

#define BATCH_STRIDE 131072  // shorts per batch in ebfF/ebfT (256 chunks * 512)
#define GSP_STRIDE 32768     // shorts per batch in gspF (64 chunks * 512)

__device__ __forceinline__ unsigned short f2bf(float f) {
  unsigned u = __float_as_uint(f);
  u += 0x7fff + ((u >> 16) & 1);  // RNE
  return (unsigned short)(u >> 16);
}
__device__ __forceinline__ float bf2f(unsigned short v) {
  return __uint_as_float(((unsigned)v) << 16);
}
__device__ __forceinline__ unsigned packbf(float a, float b) {
  __hip_bfloat162 h = __float22bfloat162_rn(float2{a, b});
  unsigned u; __builtin_memcpy(&u, &h, 4); return u;
}
__device__ __forceinline__ short8 mk8(unsigned a, unsigned b, unsigned c, unsigned d) {
  union { unsigned u[4]; short8 s; } x;
  x.u[0] = a; x.u[1] = b; x.u[2] = c; x.u[3] = d; return x.s;
}
__device__ __forceinline__ float waveSum(float v) {
#pragma unroll
  for (int k = 32; k >= 1; k >>= 1) v += __shfl_xor(v, k, 64);
  return v;
}

// async DMA one 512-short chunk (1024 B): wave-uniform LDS base + lane*16
__device__ __forceinline__ void stage1k(const unsigned short* g, unsigned short* l, int lane) {
  __builtin_amdgcn_global_load_lds(
      (const __attribute__((address_space(1))) unsigned int*)(g + lane * 8),
      (__attribute__((address_space(3))) unsigned int*)l, 16, 0, 0);
}

// C-layout (col=lane&31, row=(rg&3)+8*(rg>>2)+4*lh) -> B-operand chunks for a
// 32-wide k-range. Input: 8 packed dwords d[k]=(rows 2k,2k+1). Output 2 chunks.
__device__ __forceinline__ void c2b(const unsigned* d, int lh, short8* b0, short8* b1) {
  unsigned s0 = lh ? d[0] : d[2];
  unsigned s1 = lh ? d[1] : d[3];
  unsigned s2 = lh ? d[4] : d[6];
  unsigned s3 = lh ? d[5] : d[7];
  unsigned r0 = (unsigned)__shfl_xor((int)s0, 32, 64);
  unsigned r1 = (unsigned)__shfl_xor((int)s1, 32, 64);
  unsigned r2 = (unsigned)__shfl_xor((int)s2, 32, 64);
  unsigned r3 = (unsigned)__shfl_xor((int)s3, 32, 64);
  *b0 = (lh == 0) ? mk8(d[0], d[1], r0, r1) : mk8(r0, r1, d[2], d[3]);
  *b1 = (lh == 0) ? mk8(d[4], d[5], r2, r3) : mk8(r2, r3, d[6], d[7]);
}

// ---- convert: fp32 -> SQDS-scaled bf16 fragA (ebfF), g*SQDS-scaled fragT
//      (ebfT), gsp A-frags ([g; g*sp]), steps, ws init ----
__global__ __launch_bounds__(256) void convert_kernel(
    const float* __restrict__ embs, const int* __restrict__ fi,
    const int* __restrict__ vl, unsigned short* __restrict__ ebfF,
    unsigned short* __restrict__ ebfT, unsigned short* __restrict__ gspF,
    float* __restrict__ steps, float* __restrict__ acc, unsigned* __restrict__ cnt) {
  __shared__ unsigned short tileS[32 * 136];
  __shared__ float psum[32][8];
  __shared__ float g_sh[32], sp_sh[32];
  const int b = blockIdx.x >> 5;
  const int t0 = (blockIdx.x & 31) * 32;
  const int tid = threadIdx.x;
  const int row = tid >> 3, seg = tid & 7;

  if (blockIdx.x == 0 && tid == 0) { acc[0] = 0.f; cnt[0] = 0u; }

  const float* src = embs + (size_t)(b * T_ + t0 + row) * D_ + seg * 16;
  float4 g[4];
#pragma unroll
  for (int k = 0; k < 4; k++) g[k] = ((const float4*)src)[k];
  float s = 0.f;
  unsigned short v[16];
#pragma unroll
  for (int k = 0; k < 4; k++) {
    s += g[k].x * g[k].x + g[k].y * g[k].y + g[k].z * g[k].z + g[k].w * g[k].w;
    v[k * 4 + 0] = f2bf(g[k].x * SQDS); v[k * 4 + 1] = f2bf(g[k].y * SQDS);
    v[k * 4 + 2] = f2bf(g[k].z * SQDS); v[k * 4 + 3] = f2bf(g[k].w * SQDS);
  }
  psum[row][seg] = s;

  // fragA store (SQDS-scaled)
  unsigned short* dstA = ebfF + (size_t)b * BATCH_STRIDE + (size_t)((t0 >> 5) * 8 + seg) * 512;
  *(u16x8*)(dstA + row * 8) = *(const u16x8*)&v[0];
  *(u16x8*)(dstA + (32 + row) * 8) = *(const u16x8*)&v[8];

  *(u16x8*)&tileS[row * 136 + seg * 16] = *(const u16x8*)&v[0];
  *(u16x8*)&tileS[row * 136 + seg * 16 + 8] = *(const u16x8*)&v[8];
  __syncthreads();

  if (tid < 32) {
    float t = 0.f;
#pragma unroll
    for (int k = 0; k < 8; k++) t += psum[tid][k];
    int gr = b * T_ + t0 + tid;
    float sp = (float)fi[gr] / (float)vl[b];
    steps[gr] = sp;
    sp_sh[tid] = sp;
    g_sh[tid] = __builtin_amdgcn_exp2f(-t * NSCALE);
  }
  __syncthreads();

  // fragT store: V' = g-scaled (SQDS already in tileS), transposed
  const int c8 = tid >> 5;
  const int d0t = (c8 & 3) * 32, sc = c8 >> 2;
  const int chunk = (d0t >> 5) * 64 + (t0 >> 4) + sc;
  unsigned short* dstT = ebfT + (size_t)b * BATCH_STRIDE + (size_t)chunk * 512;
  const int dd = d0t + (tid & 31);
#pragma unroll
  for (int half = 0; half < 2; half++) {
    const int lane = half * 32 + (tid & 31);
    const int sl = sc * 16 + half * 8;
    u16x8 w;
#pragma unroll
    for (int jj = 0; jj < 8; jj++)
      w[jj] = f2bf(bf2f(tileS[(sl + jj) * 136 + dd]) * g_sh[sl + jj]);
    *(u16x8*)(dstT + lane * 8) = w;
  }

  // gsp A-frags: rows m=0 -> g, m=1 -> g*sp, rest 0 (unscaled)
  for (int idx = tid; idx < 1024; idx += 256) {
    int cchunk = idx >> 9, within = idx & 511;
    int lane = within >> 3, e = within & 7;
    int m = lane & 31, kh = lane >> 5;
    int sl = cchunk * 16 + kh * 8 + e;
    unsigned short val = 0;
    if (m == 0) val = f2bf(g_sh[sl]);
    else if (m == 1) val = f2bf(g_sh[sl] * sp_sh[sl]);
    gspF[(size_t)b * GSP_STRIDE + (size_t)((t0 >> 4) + cchunk) * 512 + within] = val;
  }
}

__global__ __launch_bounds__(256, 2) void tcc_main(
    const unsigned short* __restrict__ ebfF, const unsigned short* __restrict__ ebfT,
    const unsigned short* __restrict__ gspF, const float* __restrict__ steps,
    float* __restrict__ loss_acc, unsigned* __restrict__ cnt, float* __restrict__ out) {
  // kt[2][8192] | vt[2][8192] | gt[2][2048]  = 36864 shorts = 72 KB -> 2 blocks/CU
  __shared__ unsigned short smem[36864];
  __shared__ float blred[4];
  unsigned short* kt = smem;
  unsigned short* vt = smem + 16384;
  unsigned short* gt = smem + 32768;

  const int bx = blockIdx.x;
  const int pair = bx >> 3;
  const int tile = bx & 7;
  const int i = pair / 7;
  const int r = pair % 7;
  const int j = r + (r >= i ? 1 : 0);
  const int tid = threadIdx.x;
  const int w = tid >> 6;
  const int l = tid & 63;
  const int l31 = l & 31;
  const int lh = l >> 5;
  const int tb = tile * 128 + w * 32;   // this wave's 32 t-rows

  const unsigned short* eFi = ebfF + (size_t)i * BATCH_STRIDE;
  const unsigned short* eFj = ebfF + (size_t)j * BATCH_STRIDE;
  const unsigned short* eTj = ebfT + (size_t)j * BATCH_STRIDE;
  const unsigned short* gFi = gspF + (size_t)i * GSP_STRIDE;
  const unsigned short* gFj = gspF + (size_t)j * GSP_STRIDE;

  // Q as B-operand: fragA of e1 rows tb..tb+31 (n=t, k=d)
  short8 qf[8];
  {
    const unsigned short* qb = eFi + (size_t)((tb >> 5) * 8) * 512 + l * 8;
#pragma unroll
    for (int kc = 0; kc < 8; kc++) qf[kc] = *(const short8*)(qb + kc * 512);
  }

  f32x16 o[4], acc5;
#pragma unroll
  for (int n2 = 0; n2 < 4; n2++)
#pragma unroll
    for (int z = 0; z < 16; z++) o[n2][z] = 0.f;
#pragma unroll
  for (int z = 0; z < 16; z++) acc5[z] = 0.f;

  // ---------------- phase 1: s-tile 64, 16 iterations ----------------
#pragma unroll
  for (int u = 0; u < 4; u++) {
    stage1k(eFj + (size_t)(4 * w + u) * 512, kt + (4 * w + u) * 512, l);
    stage1k(eTj + (size_t)(w * 64 + u) * 512, vt + (4 * w + u) * 512, l);
  }
  stage1k(gFj + (size_t)w * 512, gt + w * 512, l);
  __syncthreads();

  for (int st = 0; st < 16; st++) {
    const int cur = st & 1, nxt = cur ^ 1;
    if (st < 15) {
      const int s1 = st + 1;
#pragma unroll
      for (int u = 0; u < 4; u++) {
        stage1k(eFj + (size_t)(s1 * 16 + 4 * w + u) * 512, kt + nxt * 8192 + (4 * w + u) * 512, l);
        stage1k(eTj + (size_t)(w * 64 + s1 * 4 + u) * 512, vt + nxt * 8192 + (4 * w + u) * 512, l);
      }
      stage1k(gFj + (size_t)(s1 * 4 + w) * 512, gt + nxt * 2048 + w * 512, l);
    }
    __builtin_amdgcn_sched_barrier(0);   // DMA issued BEFORE any compute

    const unsigned short* kbase = kt + cur * 8192 + l * 8;
    const unsigned short* vbase = vt + cur * 8192 + l * 8;
    const unsigned short* gbase = gt + cur * 2048 + l * 8;

    // stage A: all 4 QK chains (independent)
    f32x16 ca0, cb0, ca1, cb1;
#pragma unroll
    for (int z = 0; z < 16; z++) { ca0[z] = 0.f; cb0[z] = 0.f; ca1[z] = 0.f; cb1[z] = 0.f; }
#pragma unroll
    for (int kc = 0; kc < 4; kc++) {
      ca0 = __builtin_amdgcn_mfma_f32_32x32x16_bf16(*(const short8*)(kbase + (2 * kc) * 512), qf[2 * kc], ca0, 0, 0, 0);
      cb0 = __builtin_amdgcn_mfma_f32_32x32x16_bf16(*(const short8*)(kbase + (2 * kc + 1) * 512), qf[2 * kc + 1], cb0, 0, 0, 0);
      ca1 = __builtin_amdgcn_mfma_f32_32x32x16_bf16(*(const short8*)(kbase + (8 + 2 * kc) * 512), qf[2 * kc], ca1, 0, 0, 0);
      cb1 = __builtin_amdgcn_mfma_f32_32x32x16_bf16(*(const short8*)(kbase + (8 + 2 * kc + 1) * 512), qf[2 * kc + 1], cb1, 0, 0, 0);
    }
    // stage B: all exps (independent)
    unsigned d0[8], d1[8];
#pragma unroll
    for (int k2 = 0; k2 < 8; k2++) {
      float pa0 = __builtin_amdgcn_exp2f(ca0[2 * k2] + cb0[2 * k2]);
      float pb0 = __builtin_amdgcn_exp2f(ca0[2 * k2 + 1] + cb0[2 * k2 + 1]);
      float pa1 = __builtin_amdgcn_exp2f(ca1[2 * k2] + cb1[2 * k2]);
      float pb1 = __builtin_amdgcn_exp2f(ca1[2 * k2 + 1] + cb1[2 * k2 + 1]);
      d0[k2] = packbf(pa0, pb0);
      d1[k2] = packbf(pa1, pb1);
    }
    // stage C: both transforms
    short8 pB[4];
    c2b(d0, lh, &pB[0], &pB[1]);
    c2b(d1, lh, &pB[2], &pB[3]);
    // stage D: gsp + PV
#pragma unroll
    for (int c = 0; c < 4; c++)
      acc5 = __builtin_amdgcn_mfma_f32_32x32x16_bf16(*(const short8*)(gbase + c * 512), pB[c], acc5, 0, 0, 0);
#pragma unroll
    for (int n2 = 0; n2 < 4; n2++)
#pragma unroll
      for (int c = 0; c < 4; c++)
        o[n2] = __builtin_amdgcn_mfma_f32_32x32x16_bf16(*(const short8*)(vbase + (n2 * 4 + c) * 512), pB[c], o[n2], 0, 0, 0);
    __syncthreads();
  }

  // stage phase-2 tile 0 (overlaps interphase math)
#pragma unroll
  for (int u = 0; u < 4; u++)
    stage1k(eFi + (size_t)(4 * w + u) * 512, kt + (4 * w + u) * 512, l);
  stage1k(gFi + (size_t)w * 512, gt + w * 512, l);

  // ---- interphase: nn^T = O^T / L; phase-2 B-frags via shfl (no LDS) ----
  float Lme = acc5[0];                       // L[t] at lh=0 lanes (row 0)
  float Lo = __shfl_xor(Lme, 32, 64);
  float inv = 1.0f / (lh ? Lo : Lme);
  short8 qf2[8];
#pragma unroll
  for (int n2 = 0; n2 < 4; n2++) {
    unsigned d[8];
#pragma unroll
    for (int k2 = 0; k2 < 8; k2++)
      d[k2] = packbf(o[n2][2 * k2] * inv, o[n2][2 * k2 + 1] * inv);
    c2b(d, lh, &qf2[2 * n2], &qf2[2 * n2 + 1]);
  }

  // ---------------- phase 2: s-tile 64, 16 iterations, K + gsp only ----------------
  f32x16 acc6;
#pragma unroll
  for (int z = 0; z < 16; z++) acc6[z] = 0.f;
  __syncthreads();

  for (int st = 0; st < 16; st++) {
    const int cur = st & 1, nxt = cur ^ 1;
    if (st < 15) {
      const int s1 = st + 1;
#pragma unroll
      for (int u = 0; u < 4; u++)
        stage1k(eFi + (size_t)(s1 * 16 + 4 * w + u) * 512, kt + nxt * 8192 + (4 * w + u) * 512, l);
      stage1k(gFi + (size_t)(s1 * 4 + w) * 512, gt + nxt * 2048 + w * 512, l);
    }
    __builtin_amdgcn_sched_barrier(0);   // DMA issued BEFORE any compute

    const unsigned short* kbase = kt + cur * 8192 + l * 8;
    const unsigned short* gbase = gt + cur * 2048 + l * 8;

    f32x16 ca0, cb0, ca1, cb1;
#pragma unroll
    for (int z = 0; z < 16; z++) { ca0[z] = 0.f; cb0[z] = 0.f; ca1[z] = 0.f; cb1[z] = 0.f; }
#pragma unroll
    for (int kc = 0; kc < 4; kc++) {
      ca0 = __builtin_amdgcn_mfma_f32_32x32x16_bf16(*(const short8*)(kbase + (2 * kc) * 512), qf2[2 * kc], ca0, 0, 0, 0);
      cb0 = __builtin_amdgcn_mfma_f32_32x32x16_bf16(*(const short8*)(kbase + (2 * kc + 1) * 512), qf2[2 * kc + 1], cb0, 0, 0, 0);
      ca1 = __builtin_amdgcn_mfma_f32_32x32x16_bf16(*(const short8*)(kbase + (8 + 2 * kc) * 512), qf2[2 * kc], ca1, 0, 0, 0);
      cb1 = __builtin_amdgcn_mfma_f32_32x32x16_bf16(*(const short8*)(kbase + (8 + 2 * kc + 1) * 512), qf2[2 * kc + 1], cb1, 0, 0, 0);
    }
    unsigned d0[8], d1[8];
#pragma unroll
    for (int k2 = 0; k2 < 8; k2++) {
      float pa0 = __builtin_amdgcn_exp2f(ca0[2 * k2] + cb0[2 * k2]);
      float pb0 = __builtin_amdgcn_exp2f(ca0[2 * k2 + 1] + cb0[2 * k2 + 1]);
      float pa1 = __builtin_amdgcn_exp2f(ca1[2 * k2] + cb1[2 * k2]);
      float pb1 = __builtin_amdgcn_exp2f(ca1[2 * k2 + 1] + cb1[2 * k2 + 1]);
      d0[k2] = packbf(pa0, pb0);
      d1[k2] = packbf(pa1, pb1);
    }
    short8 pB[4];
    c2b(d0, lh, &pB[0], &pB[1]);
    c2b(d1, lh, &pB[2], &pB[3]);
#pragma unroll
    for (int c = 0; c < 4; c++)
      acc6 = __builtin_amdgcn_mfma_f32_32x32x16_bf16(*(const short8*)(gbase + c * 512), pB[c], acc6, 0, 0, 0);
    __syncthreads();
  }

  // ---- epilogue: pred = tp/L2 (rows 0,1 at lh=0 lanes), MSE, fused finalize ----
  float local = 0.f;
  if (lh == 0) {
    float pred = acc6[1] / acc6[0];
    float tt = steps[i * T_ + tb + l31];
    float dd = pred - tt;
    local = dd * dd;
  }
  local = waveSum(local);
  if (l == 0) blred[w] = local;
  __syncthreads();
  if (tid == 0) {
    atomicAdd(loss_acc, blred[0] + blred[1] + blred[2] + blred[3]);
    __threadfence();
    unsigned old = atomicAdd(cnt, 1u);
    if (old == (unsigned)(gridDim.x - 1)) {
      float v = atomicAdd(loss_acc, 0.0f);   // device-scope atomic read
      out[0] = v * (1.0f / (float)(NPAIR * T_));
    }
  }
}

extern "C" void kernel_launch(void* const* d_in, const int* in_sizes, int n_in,
                              void* d_out, int out_size, void* d_ws, size_t ws_size,
                              hipStream_t stream) {
  const float* embs = (const float*)d_in[0];
  const int* frame_idxs = (const int*)d_in[1];
  const int* video_len = (const int*)d_in[2];
  float* out = (float*)d_out;

  char* ws = (char*)d_ws;
  float* acc = (float*)ws;                                      // @0
  unsigned* cnt = (unsigned*)(ws + 512);                        // @512
  float* steps = (float*)(ws + 4096);                           // 8192 f32
  unsigned short* ebfF = (unsigned short*)(ws + 65536);         // 2 MB
  unsigned short* ebfT = ebfF + (size_t)8 * BATCH_STRIDE;       // 2 MB
  unsigned short* gspF = ebfT + (size_t)8 * BATCH_STRIDE;       // 512 KB

  convert_kernel<<<dim3(256), dim3(256), 0, stream>>>(embs, frame_idxs, video_len,
                                                      ebfF, ebfT, gspF, steps, acc, cnt);
  tcc_main<<<dim3(NPAIR * 8), dim3(256), 0, stream>>>(ebfF, ebfT, gspF, steps, acc, cnt, out);
}